// Round 1
// baseline (5255.083 us; speedup 1.0000x reference)
//
#include <hip/hip_runtime.h>
#include <hip/hip_bf16.h>

#define N_NODES 50000
#define E_EDGES 800000
#define HD 512
#define H_HEADS 4
#define D_DIM 128

// ---------------- GEMM: C[N,512] = A[N,K] @ W[K,512], f32 ----------------
__global__ void gemm512(const float* __restrict__ A, const float* __restrict__ W,
                        float* __restrict__ C, int nrows, int K) {
  __shared__ float As[16][64];
  __shared__ float Ws[16][64];
  const int tid = threadIdx.x;
  const int tx = tid & 15, ty = tid >> 4;
  const int row0 = blockIdx.y * 64, col0 = blockIdx.x * 64;
  float acc[4][4] = {};
  const int ar = tid >> 2;       // 0..63  (A tile row)
  const int ac = (tid & 3) * 4;  // 0,4,8,12 (A tile col)
  int arow = row0 + ar;
  if (arow >= nrows) arow = nrows - 1;  // clamp; stores are guarded
  const int wr = tid >> 4;       // 0..15 (W tile row)
  const int wc = (tid & 15) * 4; // 0..60 (W tile col)
  for (int k0 = 0; k0 < K; k0 += 16) {
    float4 av = *(const float4*)(A + (size_t)arow * K + k0 + ac);
    float4 wv = *(const float4*)(W + (size_t)(k0 + wr) * HD + col0 + wc);
    As[ac + 0][ar] = av.x;
    As[ac + 1][ar] = av.y;
    As[ac + 2][ar] = av.z;
    As[ac + 3][ar] = av.w;
    *(float4*)&Ws[wr][wc] = wv;
    __syncthreads();
#pragma unroll
    for (int k = 0; k < 16; ++k) {
      float4 a = *(const float4*)&As[k][ty * 4];
      float4 w = *(const float4*)&Ws[k][tx * 4];
      float aa[4] = {a.x, a.y, a.z, a.w};
      float ww[4] = {w.x, w.y, w.z, w.w};
#pragma unroll
      for (int i = 0; i < 4; ++i)
#pragma unroll
        for (int j = 0; j < 4; ++j)
          acc[i][j] = fmaf(aa[i], ww[j], acc[i][j]);
    }
    __syncthreads();
  }
#pragma unroll
  for (int i = 0; i < 4; ++i) {
    int r = row0 + ty * 4 + i;
    if (r < nrows) {
      float4 v = {acc[i][0], acc[i][1], acc[i][2], acc[i][3]};
      *(float4*)(C + (size_t)r * HD + col0 + tx * 4) = v;
    }
  }
}

// ---------------- el/er: wave per (node, head) ----------------
__global__ void eler_kernel(const float* __restrict__ feat, const float* __restrict__ al,
                            const float* __restrict__ ar, float* __restrict__ el,
                            float* __restrict__ er) {
  int n = blockIdx.x;
  int h = threadIdx.x >> 6;
  int lane = threadIdx.x & 63;
  const float* f = feat + (size_t)n * HD + h * D_DIM;
  const float* alh = al + h * D_DIM;
  const float* arh = ar + h * D_DIM;
  float f0 = f[lane], f1 = f[lane + 64];
  float sl = f0 * alh[lane] + f1 * alh[lane + 64];
  float sr = f0 * arh[lane] + f1 * arh[lane + 64];
#pragma unroll
  for (int off = 32; off >= 1; off >>= 1) {
    sl += __shfl_xor(sl, off);
    sr += __shfl_xor(sr, off);
  }
  if (lane == 0) {
    el[n * 4 + h] = sl;
    er[n * 4 + h] = sr;
  }
}

// monotonic float<->uint encoding for atomicMax
__device__ __forceinline__ unsigned f2key(float f) {
  unsigned u = __float_as_uint(f);
  return (u & 0x80000000u) ? ~u : (u | 0x80000000u);
}
__device__ __forceinline__ float key2f(unsigned k) {
  unsigned u = (k & 0x80000000u) ? (k & 0x7FFFFFFFu) : ~k;
  return __uint_as_float(u);
}

// ---------------- edge pass 1: e = leaky_relu(el[src]+er[dst]); segment max ----------------
__global__ void edge_pass1(const int* __restrict__ src, const int* __restrict__ dst,
                           const float* __restrict__ el, const float* __restrict__ er,
                           float* __restrict__ eval, unsigned* __restrict__ emax) {
  int e = blockIdx.x * blockDim.x + threadIdx.x;
  if (e >= E_EDGES) return;
  int s = src[e], d = dst[e];
  float4 l = *(const float4*)(el + (size_t)s * 4);
  float4 r = *(const float4*)(er + (size_t)d * 4);
  float lv[4] = {l.x, l.y, l.z, l.w};
  float rv[4] = {r.x, r.y, r.z, r.w};
#pragma unroll
  for (int h = 0; h < 4; ++h) {
    float v = lv[h] + rv[h];
    v = (v > 0.0f) ? v : 0.2f * v;
    eval[(size_t)e * 4 + h] = v;
    atomicMax(&emax[(size_t)d * 4 + h], f2key(v));
  }
}

// ---------------- edge pass 2: ee = exp(e - emax[dst]); segment sum ----------------
__global__ void edge_pass2(const int* __restrict__ dst, float* __restrict__ eval,
                           const unsigned* __restrict__ emax, float* __restrict__ denom) {
  int e = blockIdx.x * blockDim.x + threadIdx.x;
  if (e >= E_EDGES) return;
  int d = dst[e];
#pragma unroll
  for (int h = 0; h < 4; ++h) {
    float m = key2f(emax[(size_t)d * 4 + h]);
    float ee = expf(eval[(size_t)e * 4 + h] - m);
    eval[(size_t)e * 4 + h] = ee;
    atomicAdd(&denom[(size_t)d * 4 + h], ee);
  }
}

// ---------------- aggregate: out[dst] += feat[src] * a ----------------
__global__ void aggregate(const int* __restrict__ src, const int* __restrict__ dst,
                          const float* __restrict__ eval, const float* __restrict__ denom,
                          const float* __restrict__ feat, float* __restrict__ out) {
  int e = blockIdx.x;
  int s = src[e], d = dst[e];
  int tid = threadIdx.x;
#pragma unroll
  for (int i = 0; i < 2; ++i) {
    int idx = tid + i * 256;
    int h = idx >> 7;
    float a = eval[(size_t)e * 4 + h] / denom[(size_t)d * 4 + h];
    atomicAdd(&out[(size_t)d * HD + idx], feat[(size_t)s * HD + idx] * a);
  }
}

// ---------------- bias + relu + mean over heads ----------------
__global__ void relu_mean(const float* __restrict__ agg, const float* __restrict__ bias,
                          float* __restrict__ outh) {
  int i = blockIdx.x * blockDim.x + threadIdx.x;
  if (i >= N_NODES * D_DIM) return;
  int n = i >> 7, d = i & 127;
  float sacc = 0.0f;
#pragma unroll
  for (int h = 0; h < 4; ++h) {
    float v = agg[(size_t)n * HD + h * D_DIM + d] + bias[h * D_DIM + d];
    sacc += (v > 0.0f) ? v : 0.0f;
  }
  outh[i] = sacc * 0.25f;
}

// ---------------- readout: column sums ----------------
__global__ void colsum(const float* __restrict__ hbuf, float* __restrict__ hg) {
  int d = threadIdx.x;  // 128
  float s = 0.0f;
  for (int n = blockIdx.x; n < N_NODES; n += gridDim.x)
    s += hbuf[(size_t)n * D_DIM + d];
  atomicAdd(&hg[d], s);
}

__global__ void final_k(const float* __restrict__ hg, const float* __restrict__ Wc,
                        const float* __restrict__ bc, float* __restrict__ out) {
  int l = threadIdx.x;  // 64
  float v = hg[l] * Wc[l] + hg[l + 64] * Wc[l + 64];
#pragma unroll
  for (int off = 32; off >= 1; off >>= 1) v += __shfl_xor(v, off);
  if (l == 0) {
    float x = v * (1.0f / N_NODES) + bc[0];
    out[0] = 1.0f / (1.0f + expf(-x));
  }
}

extern "C" void kernel_launch(void* const* d_in, const int* in_sizes, int n_in,
                              void* d_out, int out_size, void* d_ws, size_t ws_size,
                              hipStream_t stream) {
  const float* nfeats = (const float*)d_in[0];
  const float* W1 = (const float*)d_in[1];
  const float* al1 = (const float*)d_in[2];
  const float* ar1 = (const float*)d_in[3];
  const float* b1 = (const float*)d_in[4];
  const float* W2 = (const float*)d_in[5];
  const float* al2 = (const float*)d_in[6];
  const float* ar2 = (const float*)d_in[7];
  const float* b2 = (const float*)d_in[8];
  const float* W3 = (const float*)d_in[9];
  const float* al3 = (const float*)d_in[10];
  const float* ar3 = (const float*)d_in[11];
  const float* b3 = (const float*)d_in[12];
  const float* Wc = (const float*)d_in[13];
  const float* bc = (const float*)d_in[14];
  const int* src = (const int*)d_in[15];
  const int* dst = (const int*)d_in[16];
  float* out = (float*)d_out;

  float* feat = (float*)d_ws;                          // N*512
  float* agg = feat + (size_t)N_NODES * HD;            // N*512
  float* hbuf = agg + (size_t)N_NODES * HD;            // N*128
  float* el = hbuf + (size_t)N_NODES * D_DIM;          // N*4
  float* er = el + (size_t)N_NODES * 4;                // N*4
  unsigned* emax = (unsigned*)(er + (size_t)N_NODES * 4);  // N*4
  float* denom = (float*)(emax + (size_t)N_NODES * 4);     // N*4
  float* eval = denom + (size_t)N_NODES * 4;           // E*4
  float* hg = eval + (size_t)E_EDGES * 4;              // 128

  auto run_layer = [&](const float* X, int K, const float* Wm, const float* alv,
                       const float* arv, const float* bv) {
    dim3 g(HD / 64, (N_NODES + 63) / 64);
    gemm512<<<g, 256, 0, stream>>>(X, Wm, feat, N_NODES, K);
    eler_kernel<<<N_NODES, 256, 0, stream>>>(feat, alv, arv, el, er);
    hipMemsetAsync(emax, 0, (size_t)N_NODES * 4 * sizeof(unsigned), stream);
    hipMemsetAsync(denom, 0, (size_t)N_NODES * 4 * sizeof(float), stream);
    edge_pass1<<<(E_EDGES + 255) / 256, 256, 0, stream>>>(src, dst, el, er, eval, emax);
    edge_pass2<<<(E_EDGES + 255) / 256, 256, 0, stream>>>(dst, eval, emax, denom);
    hipMemsetAsync(agg, 0, (size_t)N_NODES * HD * sizeof(float), stream);
    aggregate<<<E_EDGES, 256, 0, stream>>>(src, dst, eval, denom, feat, agg);
    relu_mean<<<(N_NODES * D_DIM + 255) / 256, 256, 0, stream>>>(agg, bv, hbuf);
  };

  run_layer(nfeats, 256, W1, al1, ar1, b1);
  run_layer(hbuf, 128, W2, al2, ar2, b2);
  run_layer(hbuf, 128, W3, al3, ar3, b3);

  hipMemsetAsync(hg, 0, 128 * sizeof(float), stream);
  colsum<<<1024, 128, 0, stream>>>(hbuf, hg);
  final_k<<<1, 64, 0, stream>>>(hg, Wc, bc, out);
}

// Round 2
// 2224.567 us; speedup vs baseline: 2.3623x; 2.3623x over previous
//
#include <hip/hip_runtime.h>
#include <hip/hip_bf16.h>

#define N_NODES 50000
#define E_EDGES 800000
#define HD 512
#define H_HEADS 4
#define D_DIM 128

// ---------------- GEMM: C[N,512] = A[N,K] @ W[K,512], f32 ----------------
__global__ void gemm512(const float* __restrict__ A, const float* __restrict__ W,
                        float* __restrict__ C, int nrows, int K) {
  __shared__ float As[16][64];
  __shared__ float Ws[16][64];
  const int tid = threadIdx.x;
  const int tx = tid & 15, ty = tid >> 4;
  const int row0 = blockIdx.y * 64, col0 = blockIdx.x * 64;
  float acc[4][4] = {};
  const int ar = tid >> 2;       // 0..63  (A tile row)
  const int ac = (tid & 3) * 4;  // 0,4,8,12 (A tile col)
  int arow = row0 + ar;
  if (arow >= nrows) arow = nrows - 1;  // clamp; stores are guarded
  const int wr = tid >> 4;       // 0..15 (W tile row)
  const int wc = (tid & 15) * 4; // 0..60 (W tile col)
  for (int k0 = 0; k0 < K; k0 += 16) {
    float4 av = *(const float4*)(A + (size_t)arow * K + k0 + ac);
    float4 wv = *(const float4*)(W + (size_t)(k0 + wr) * HD + col0 + wc);
    As[ac + 0][ar] = av.x;
    As[ac + 1][ar] = av.y;
    As[ac + 2][ar] = av.z;
    As[ac + 3][ar] = av.w;
    *(float4*)&Ws[wr][wc] = wv;
    __syncthreads();
#pragma unroll
    for (int k = 0; k < 16; ++k) {
      float4 a = *(const float4*)&As[k][ty * 4];
      float4 w = *(const float4*)&Ws[k][tx * 4];
      float aa[4] = {a.x, a.y, a.z, a.w};
      float ww[4] = {w.x, w.y, w.z, w.w};
#pragma unroll
      for (int i = 0; i < 4; ++i)
#pragma unroll
        for (int j = 0; j < 4; ++j)
          acc[i][j] = fmaf(aa[i], ww[j], acc[i][j]);
    }
    __syncthreads();
  }
#pragma unroll
  for (int i = 0; i < 4; ++i) {
    int r = row0 + ty * 4 + i;
    if (r < nrows) {
      float4 v = {acc[i][0], acc[i][1], acc[i][2], acc[i][3]};
      *(float4*)(C + (size_t)r * HD + col0 + tx * 4) = v;
    }
  }
}

// ---------------- el/er: wave per (node, head) ----------------
__global__ void eler_kernel(const float* __restrict__ feat, const float* __restrict__ al,
                            const float* __restrict__ ar, float* __restrict__ el,
                            float* __restrict__ er) {
  int n = blockIdx.x;
  int h = threadIdx.x >> 6;
  int lane = threadIdx.x & 63;
  const float* f = feat + (size_t)n * HD + h * D_DIM;
  const float* alh = al + h * D_DIM;
  const float* arh = ar + h * D_DIM;
  float f0 = f[lane], f1 = f[lane + 64];
  float sl = f0 * alh[lane] + f1 * alh[lane + 64];
  float sr = f0 * arh[lane] + f1 * arh[lane + 64];
#pragma unroll
  for (int off = 32; off >= 1; off >>= 1) {
    sl += __shfl_xor(sl, off);
    sr += __shfl_xor(sr, off);
  }
  if (lane == 0) {
    el[n * 4 + h] = sl;
    er[n * 4 + h] = sr;
  }
}

// monotonic float<->uint encoding for atomicMax
__device__ __forceinline__ unsigned f2key(float f) {
  unsigned u = __float_as_uint(f);
  return (u & 0x80000000u) ? ~u : (u | 0x80000000u);
}
__device__ __forceinline__ float key2f(unsigned k) {
  unsigned u = (k & 0x80000000u) ? (k & 0x7FFFFFFFu) : ~k;
  return __uint_as_float(u);
}

// ---------------- CSR build ----------------
__global__ void histo_kernel(const int* __restrict__ dst, unsigned* __restrict__ deg) {
  int e = blockIdx.x * blockDim.x + threadIdx.x;
  if (e >= E_EDGES) return;
  atomicAdd(&deg[dst[e]], 1u);
}

// single-workgroup exclusive scan over N_NODES (1024 threads, chunked)
__global__ void scan_kernel(const unsigned* __restrict__ deg, unsigned* __restrict__ off,
                            unsigned* __restrict__ cursor) {
  __shared__ unsigned warp_sums[16];
  __shared__ unsigned carry_s;
  const int tid = threadIdx.x;  // 1024
  const int wid = tid >> 6;
  if (tid == 0) carry_s = 0;
  __syncthreads();
  for (int base = 0; base < N_NODES; base += 1024) {
    int i = base + tid;
    unsigned v = (i < N_NODES) ? deg[i] : 0u;
    unsigned x = v;
#pragma unroll
    for (int o = 1; o < 64; o <<= 1) {
      unsigned y = __shfl_up(x, o);
      if ((tid & 63) >= o) x += y;
    }
    if ((tid & 63) == 63) warp_sums[wid] = x;
    __syncthreads();  // A
    if (tid < 16) {
      unsigned s = warp_sums[tid];
#pragma unroll
      for (int o = 1; o < 16; o <<= 1) {
        unsigned y = __shfl_up(s, o);
        if (tid >= o) s += y;
      }
      warp_sums[tid] = s;  // inclusive scan of warp sums
    }
    __syncthreads();  // B
    unsigned carry = carry_s;
    unsigned wprev = (wid > 0) ? warp_sums[wid - 1] : 0u;
    unsigned excl = carry + wprev + (x - v);
    if (i < N_NODES) {
      off[i] = excl;
      cursor[i] = excl;
    }
    __syncthreads();  // C
    if (tid == 0) carry_s = carry + warp_sums[15];
    __syncthreads();  // D
  }
  if (tid == 0) off[N_NODES] = carry_s;
}

__global__ void scatter_kernel(const int* __restrict__ src, const int* __restrict__ dst,
                               unsigned* __restrict__ cursor, int* __restrict__ csr_src,
                               int* __restrict__ csr_eid) {
  int e = blockIdx.x * blockDim.x + threadIdx.x;
  if (e >= E_EDGES) return;
  int d = dst[e];
  unsigned pos = atomicAdd(&cursor[d], 1u);
  csr_src[pos] = src[e];
  csr_eid[pos] = e;
}

// ---------------- edge pass 1: e = leaky_relu(el[src]+er[dst]); segment max ----------------
__global__ void edge_pass1(const int* __restrict__ src, const int* __restrict__ dst,
                           const float* __restrict__ el, const float* __restrict__ er,
                           float* __restrict__ eval, unsigned* __restrict__ emax) {
  int e = blockIdx.x * blockDim.x + threadIdx.x;
  if (e >= E_EDGES) return;
  int s = src[e], d = dst[e];
  float4 l = *(const float4*)(el + (size_t)s * 4);
  float4 r = *(const float4*)(er + (size_t)d * 4);
  float lv[4] = {l.x, l.y, l.z, l.w};
  float rv[4] = {r.x, r.y, r.z, r.w};
#pragma unroll
  for (int h = 0; h < 4; ++h) {
    float v = lv[h] + rv[h];
    v = (v > 0.0f) ? v : 0.2f * v;
    eval[(size_t)e * 4 + h] = v;
    atomicMax(&emax[(size_t)d * 4 + h], f2key(v));
  }
}

// ---------------- edge pass 2: ee = exp(e - emax[dst]); segment sum ----------------
__global__ void edge_pass2(const int* __restrict__ dst, float* __restrict__ eval,
                           const unsigned* __restrict__ emax, float* __restrict__ denom) {
  int e = blockIdx.x * blockDim.x + threadIdx.x;
  if (e >= E_EDGES) return;
  int d = dst[e];
#pragma unroll
  for (int h = 0; h < 4; ++h) {
    float m = key2f(emax[(size_t)d * 4 + h]);
    float ee = expf(eval[(size_t)e * 4 + h] - m);
    eval[(size_t)e * 4 + h] = ee;
    atomicAdd(&denom[(size_t)d * 4 + h], ee);
  }
}

// ---------------- CSR aggregate + bias + relu + head-mean, atomic-free ----------------
__global__ void aggregate_csr(const unsigned* __restrict__ off, const int* __restrict__ csr_src,
                              const int* __restrict__ csr_eid, const float* __restrict__ eval,
                              const float* __restrict__ denom, const float* __restrict__ feat,
                              const float* __restrict__ bias, float* __restrict__ hbuf) {
  int n = blockIdx.x;
  int t = threadIdx.x;  // 128
  unsigned beg = off[n], end = off[n + 1];
  float4 dn = *(const float4*)(denom + (size_t)n * 4);
  float inv0 = 1.0f / dn.x, inv1 = 1.0f / dn.y, inv2 = 1.0f / dn.z, inv3 = 1.0f / dn.w;
  float acc0 = 0.f, acc1 = 0.f, acc2 = 0.f, acc3 = 0.f;
  for (unsigned j = beg; j < end; ++j) {
    int s = csr_src[j];
    int e = csr_eid[j];
    float4 ev = *(const float4*)(eval + (size_t)e * 4);
    const float* f = feat + (size_t)s * HD + t;
    acc0 = fmaf(f[0],   ev.x * inv0, acc0);
    acc1 = fmaf(f[128], ev.y * inv1, acc1);
    acc2 = fmaf(f[256], ev.z * inv2, acc2);
    acc3 = fmaf(f[384], ev.w * inv3, acc3);
  }
  float r = 0.f;
  r += fmaxf(acc0 + bias[t], 0.f);
  r += fmaxf(acc1 + bias[128 + t], 0.f);
  r += fmaxf(acc2 + bias[256 + t], 0.f);
  r += fmaxf(acc3 + bias[384 + t], 0.f);
  hbuf[(size_t)n * D_DIM + t] = r * 0.25f;
}

// ---------------- readout: column sums ----------------
__global__ void colsum(const float* __restrict__ hbuf, float* __restrict__ hg) {
  int d = threadIdx.x;  // 128
  float s = 0.0f;
  for (int n = blockIdx.x; n < N_NODES; n += gridDim.x)
    s += hbuf[(size_t)n * D_DIM + d];
  atomicAdd(&hg[d], s);
}

__global__ void final_k(const float* __restrict__ hg, const float* __restrict__ Wc,
                        const float* __restrict__ bc, float* __restrict__ out) {
  int l = threadIdx.x;  // 64
  float v = hg[l] * Wc[l] + hg[l + 64] * Wc[l + 64];
#pragma unroll
  for (int off = 32; off >= 1; off >>= 1) v += __shfl_xor(v, off);
  if (l == 0) {
    float x = v * (1.0f / N_NODES) + bc[0];
    out[0] = 1.0f / (1.0f + expf(-x));
  }
}

extern "C" void kernel_launch(void* const* d_in, const int* in_sizes, int n_in,
                              void* d_out, int out_size, void* d_ws, size_t ws_size,
                              hipStream_t stream) {
  const float* nfeats = (const float*)d_in[0];
  const float* W1 = (const float*)d_in[1];
  const float* al1 = (const float*)d_in[2];
  const float* ar1 = (const float*)d_in[3];
  const float* b1 = (const float*)d_in[4];
  const float* W2 = (const float*)d_in[5];
  const float* al2 = (const float*)d_in[6];
  const float* ar2 = (const float*)d_in[7];
  const float* b2 = (const float*)d_in[8];
  const float* W3 = (const float*)d_in[9];
  const float* al3 = (const float*)d_in[10];
  const float* ar3 = (const float*)d_in[11];
  const float* b3 = (const float*)d_in[12];
  const float* Wc = (const float*)d_in[13];
  const float* bc = (const float*)d_in[14];
  const int* src = (const int*)d_in[15];
  const int* dst = (const int*)d_in[16];
  float* out = (float*)d_out;

  // workspace layout (floats unless noted)
  float* feat = (float*)d_ws;                                // N*512
  float* hbuf = feat + (size_t)N_NODES * HD;                 // N*128
  float* el = hbuf + (size_t)N_NODES * D_DIM;                // N*4
  float* er = el + (size_t)N_NODES * 4;                      // N*4
  unsigned* emax = (unsigned*)(er + (size_t)N_NODES * 4);    // N*4
  float* denom = (float*)(emax + (size_t)N_NODES * 4);       // N*4
  float* eval = denom + (size_t)N_NODES * 4;                 // E*4
  float* hg = eval + (size_t)E_EDGES * 4;                    // 128
  unsigned* deg = (unsigned*)(hg + 128);                     // N
  unsigned* offv = deg + N_NODES;                            // N+1
  unsigned* cursor = offv + N_NODES + 1;                     // N
  int* csr_src = (int*)(cursor + N_NODES);                   // E
  int* csr_eid = csr_src + E_EDGES;                          // E

  // ---- build CSR once (dst constant across layers) ----
  hipMemsetAsync(deg, 0, (size_t)N_NODES * sizeof(unsigned), stream);
  histo_kernel<<<(E_EDGES + 255) / 256, 256, 0, stream>>>(dst, deg);
  scan_kernel<<<1, 1024, 0, stream>>>(deg, offv, cursor);
  scatter_kernel<<<(E_EDGES + 255) / 256, 256, 0, stream>>>(src, dst, cursor, csr_src, csr_eid);

  auto run_layer = [&](const float* X, int K, const float* Wm, const float* alv,
                       const float* arv, const float* bv) {
    dim3 g(HD / 64, (N_NODES + 63) / 64);
    gemm512<<<g, 256, 0, stream>>>(X, Wm, feat, N_NODES, K);
    eler_kernel<<<N_NODES, 256, 0, stream>>>(feat, alv, arv, el, er);
    hipMemsetAsync(emax, 0, (size_t)N_NODES * 4 * sizeof(unsigned), stream);
    hipMemsetAsync(denom, 0, (size_t)N_NODES * 4 * sizeof(float), stream);
    edge_pass1<<<(E_EDGES + 255) / 256, 256, 0, stream>>>(src, dst, el, er, eval, emax);
    edge_pass2<<<(E_EDGES + 255) / 256, 256, 0, stream>>>(dst, eval, emax, denom);
    aggregate_csr<<<N_NODES, 128, 0, stream>>>(offv, csr_src, csr_eid, eval, denom, feat, bv, hbuf);
  };

  run_layer(nfeats, 256, W1, al1, ar1, b1);
  run_layer(hbuf, 128, W2, al2, ar2, b2);
  run_layer(hbuf, 128, W3, al3, ar3, b3);

  hipMemsetAsync(hg, 0, 128 * sizeof(float), stream);
  colsum<<<1024, 128, 0, stream>>>(hbuf, hg);
  final_k<<<1, 64, 0, stream>>>(hg, Wc, bc, out);
}

// Round 3
// 1843.102 us; speedup vs baseline: 2.8512x; 1.2070x over previous
//
#include <hip/hip_runtime.h>
#include <hip/hip_bf16.h>

#define N_NODES 50000
#define E_EDGES 800000
#define HD 512
#define H_HEADS 4
#define D_DIM 128

typedef __attribute__((ext_vector_type(8))) short bf16x8;
typedef __attribute__((ext_vector_type(4))) float f32x4;

__device__ __forceinline__ unsigned short f2b(float f) {
  unsigned u = __float_as_uint(f);
  u += 0x7FFFu + ((u >> 16) & 1u);  // RNE
  return (unsigned short)(u >> 16);
}
__device__ __forceinline__ float b2f(unsigned short s) {
  return __uint_as_float(((unsigned)s) << 16);
}

// ---------------- cast f32 -> bf16, 4 elems/thread ----------------
__global__ void cast_f2b(const float* __restrict__ in, unsigned short* __restrict__ out, int n4) {
  int i = blockIdx.x * blockDim.x + threadIdx.x;
  if (i >= n4) return;
  float4 v = *(const float4*)(in + (size_t)i * 4);
  ushort4 o;
  o.x = f2b(v.x); o.y = f2b(v.y); o.z = f2b(v.z); o.w = f2b(v.w);
  *(ushort4*)(out + (size_t)i * 4) = o;
}

// ---------------- W[K,512] f32 -> WT[512,K] bf16 ----------------
__global__ void transpose_cast(const float* __restrict__ W, unsigned short* __restrict__ WT, int K) {
  int idx = blockIdx.x * blockDim.x + threadIdx.x;
  if (idx >= K * HD) return;
  int k = idx >> 9, c = idx & (HD - 1);
  WT[(size_t)c * K + k] = f2b(W[idx]);
}

// ---------------- MFMA GEMM: feat[N,512](bf16) = X[N,K](bf16) @ W ----------------
// block: 64 rows x 128 cols, 4 waves (wave w -> rows [16w,16w+16))
__global__ __launch_bounds__(256) void gemm_mfma(const unsigned short* __restrict__ X,
                                                 const unsigned short* __restrict__ WT,
                                                 unsigned short* __restrict__ feat, int K) {
  const int tid = threadIdx.x;
  const int w = tid >> 6, l = tid & 63;
  const int row0 = blockIdx.x * 64 + w * 16;
  const int col0 = blockIdx.y * 128;
  const int lr = l & 15;        // A-row / B-col within tile
  const int lk = (l >> 4) * 8;  // k-offset within 32
  f32x4 acc[8] = {};
  int arow = row0 + lr;
  if (arow >= N_NODES) arow = N_NODES - 1;  // clamp; stores guarded
  const unsigned short* aptr = X + (size_t)arow * K + lk;
  for (int k0 = 0; k0 < K; k0 += 32) {
    bf16x8 a = *(const bf16x8*)(aptr + k0);
#pragma unroll
    for (int c = 0; c < 8; ++c) {
      const unsigned short* bp = WT + (size_t)(col0 + c * 16 + lr) * K + k0 + lk;
      bf16x8 b = *(const bf16x8*)bp;
      acc[c] = __builtin_amdgcn_mfma_f32_16x16x32_bf16(a, b, acc[c], 0, 0, 0);
    }
  }
  const int orow = row0 + (l >> 4) * 4;
#pragma unroll
  for (int c = 0; c < 8; ++c) {
#pragma unroll
    for (int i = 0; i < 4; ++i) {
      int r = orow + i;
      if (r < N_NODES) feat[(size_t)r * HD + col0 + c * 16 + lr] = f2b(acc[c][i]);
    }
  }
}

// ---------------- el/er: wave per (node, head) ----------------
__global__ void eler_kernel(const unsigned short* __restrict__ feat, const float* __restrict__ al,
                            const float* __restrict__ ar, float* __restrict__ el,
                            float* __restrict__ er) {
  int n = blockIdx.x;
  int h = threadIdx.x >> 6;
  int lane = threadIdx.x & 63;
  const unsigned short* f = feat + (size_t)n * HD + h * D_DIM;
  const float* alh = al + h * D_DIM;
  const float* arh = ar + h * D_DIM;
  float f0 = b2f(f[lane]), f1 = b2f(f[lane + 64]);
  float sl = f0 * alh[lane] + f1 * alh[lane + 64];
  float sr = f0 * arh[lane] + f1 * arh[lane + 64];
#pragma unroll
  for (int off = 32; off >= 1; off >>= 1) {
    sl += __shfl_xor(sl, off);
    sr += __shfl_xor(sr, off);
  }
  if (lane == 0) {
    el[n * 4 + h] = sl;
    er[n * 4 + h] = sr;
  }
}

// monotonic float<->uint encoding for atomicMax
__device__ __forceinline__ unsigned f2key(float f) {
  unsigned u = __float_as_uint(f);
  return (u & 0x80000000u) ? ~u : (u | 0x80000000u);
}
__device__ __forceinline__ float key2f(unsigned k) {
  unsigned u = (k & 0x80000000u) ? (k & 0x7FFFFFFFu) : ~k;
  return __uint_as_float(u);
}

// ---------------- CSR build ----------------
__global__ void histo_kernel(const int* __restrict__ dst, unsigned* __restrict__ deg) {
  int e = blockIdx.x * blockDim.x + threadIdx.x;
  if (e >= E_EDGES) return;
  atomicAdd(&deg[dst[e]], 1u);
}

__global__ void scan_kernel(const unsigned* __restrict__ deg, unsigned* __restrict__ off,
                            unsigned* __restrict__ cursor) {
  __shared__ unsigned warp_sums[16];
  __shared__ unsigned carry_s;
  const int tid = threadIdx.x;  // 1024
  const int wid = tid >> 6;
  if (tid == 0) carry_s = 0;
  __syncthreads();
  for (int base = 0; base < N_NODES; base += 1024) {
    int i = base + tid;
    unsigned v = (i < N_NODES) ? deg[i] : 0u;
    unsigned x = v;
#pragma unroll
    for (int o = 1; o < 64; o <<= 1) {
      unsigned y = __shfl_up(x, o);
      if ((tid & 63) >= o) x += y;
    }
    if ((tid & 63) == 63) warp_sums[wid] = x;
    __syncthreads();
    if (tid < 16) {
      unsigned s = warp_sums[tid];
#pragma unroll
      for (int o = 1; o < 16; o <<= 1) {
        unsigned y = __shfl_up(s, o);
        if (tid >= o) s += y;
      }
      warp_sums[tid] = s;
    }
    __syncthreads();
    unsigned carry = carry_s;
    unsigned wprev = (wid > 0) ? warp_sums[wid - 1] : 0u;
    unsigned excl = carry + wprev + (x - v);
    if (i < N_NODES) {
      off[i] = excl;
      cursor[i] = excl;
    }
    __syncthreads();
    if (tid == 0) carry_s = carry + warp_sums[15];
    __syncthreads();
  }
  if (tid == 0) off[N_NODES] = carry_s;
}

__global__ void scatter_kernel(const int* __restrict__ src, const int* __restrict__ dst,
                               unsigned* __restrict__ cursor, int* __restrict__ csr_src,
                               int* __restrict__ csr_eid) {
  int e = blockIdx.x * blockDim.x + threadIdx.x;
  if (e >= E_EDGES) return;
  int d = dst[e];
  unsigned pos = atomicAdd(&cursor[d], 1u);
  csr_src[pos] = src[e];
  csr_eid[pos] = e;
}

// ---------------- edge pass 1 ----------------
__global__ void edge_pass1(const int* __restrict__ src, const int* __restrict__ dst,
                           const float* __restrict__ el, const float* __restrict__ er,
                           float* __restrict__ eval, unsigned* __restrict__ emax) {
  int e = blockIdx.x * blockDim.x + threadIdx.x;
  if (e >= E_EDGES) return;
  int s = src[e], d = dst[e];
  float4 l = *(const float4*)(el + (size_t)s * 4);
  float4 r = *(const float4*)(er + (size_t)d * 4);
  float lv[4] = {l.x, l.y, l.z, l.w};
  float rv[4] = {r.x, r.y, r.z, r.w};
#pragma unroll
  for (int h = 0; h < 4; ++h) {
    float v = lv[h] + rv[h];
    v = (v > 0.0f) ? v : 0.2f * v;
    eval[(size_t)e * 4 + h] = v;
    atomicMax(&emax[(size_t)d * 4 + h], f2key(v));
  }
}

// ---------------- edge pass 2 ----------------
__global__ void edge_pass2(const int* __restrict__ dst, float* __restrict__ eval,
                           const unsigned* __restrict__ emax, float* __restrict__ denom) {
  int e = blockIdx.x * blockDim.x + threadIdx.x;
  if (e >= E_EDGES) return;
  int d = dst[e];
#pragma unroll
  for (int h = 0; h < 4; ++h) {
    float m = key2f(emax[(size_t)d * 4 + h]);
    float ee = expf(eval[(size_t)e * 4 + h] - m);
    eval[(size_t)e * 4 + h] = ee;
    atomicAdd(&denom[(size_t)d * 4 + h], ee);
  }
}

// ---------------- CSR aggregate + bias + relu + head-mean -> bf16 hbuf ----------------
// 1 wave per node; thread t handles d = 2t, 2t+1 for all 4 heads
__global__ void aggregate_csr(const unsigned* __restrict__ off, const int* __restrict__ csr_src,
                              const int* __restrict__ csr_eid, const float* __restrict__ eval,
                              const float* __restrict__ denom,
                              const unsigned short* __restrict__ feat,
                              const float* __restrict__ bias, unsigned short* __restrict__ hbuf) {
  int n = blockIdx.x;
  int t = threadIdx.x;  // 64
  unsigned beg = off[n], end = off[n + 1];
  float4 dn = *(const float4*)(denom + (size_t)n * 4);
  float inv[4] = {1.0f / dn.x, 1.0f / dn.y, 1.0f / dn.z, 1.0f / dn.w};
  float acc[4][2] = {};
  for (unsigned j = beg; j < end; ++j) {
    int s = csr_src[j];
    int e = csr_eid[j];
    float4 ev = *(const float4*)(eval + (size_t)e * 4);
    float wv[4] = {ev.x * inv[0], ev.y * inv[1], ev.z * inv[2], ev.w * inv[3]};
    const unsigned short* f = feat + (size_t)s * HD + 2 * t;
#pragma unroll
    for (int h = 0; h < 4; ++h) {
      unsigned pk = *(const unsigned*)(f + h * D_DIM);
      acc[h][0] = fmaf(b2f((unsigned short)(pk & 0xFFFFu)), wv[h], acc[h][0]);
      acc[h][1] = fmaf(b2f((unsigned short)(pk >> 16)), wv[h], acc[h][1]);
    }
  }
  float r0 = 0.f, r1 = 0.f;
#pragma unroll
  for (int h = 0; h < 4; ++h) {
    r0 += fmaxf(acc[h][0] + bias[h * D_DIM + 2 * t], 0.f);
    r1 += fmaxf(acc[h][1] + bias[h * D_DIM + 2 * t + 1], 0.f);
  }
  ushort2 o;
  o.x = f2b(r0 * 0.25f);
  o.y = f2b(r1 * 0.25f);
  *(ushort2*)(hbuf + (size_t)n * D_DIM + 2 * t) = o;
}

// ---------------- readout ----------------
__global__ void colsum(const unsigned short* __restrict__ hbuf, float* __restrict__ hg) {
  int d = threadIdx.x;  // 128
  float s = 0.0f;
  for (int n = blockIdx.x; n < N_NODES; n += gridDim.x)
    s += b2f(hbuf[(size_t)n * D_DIM + d]);
  atomicAdd(&hg[d], s);
}

__global__ void final_k(const float* __restrict__ hg, const float* __restrict__ Wc,
                        const float* __restrict__ bc, float* __restrict__ out) {
  int l = threadIdx.x;  // 64
  float v = hg[l] * Wc[l] + hg[l + 64] * Wc[l + 64];
#pragma unroll
  for (int off = 32; off >= 1; off >>= 1) v += __shfl_xor(v, off);
  if (l == 0) {
    float x = v * (1.0f / N_NODES) + bc[0];
    out[0] = 1.0f / (1.0f + expf(-x));
  }
}

extern "C" void kernel_launch(void* const* d_in, const int* in_sizes, int n_in,
                              void* d_out, int out_size, void* d_ws, size_t ws_size,
                              hipStream_t stream) {
  const float* nfeats = (const float*)d_in[0];
  const float* W1 = (const float*)d_in[1];
  const float* al1 = (const float*)d_in[2];
  const float* ar1 = (const float*)d_in[3];
  const float* b1 = (const float*)d_in[4];
  const float* W2 = (const float*)d_in[5];
  const float* al2 = (const float*)d_in[6];
  const float* ar2 = (const float*)d_in[7];
  const float* b2 = (const float*)d_in[8];
  const float* W3 = (const float*)d_in[9];
  const float* al3 = (const float*)d_in[10];
  const float* ar3 = (const float*)d_in[11];
  const float* b3 = (const float*)d_in[12];
  const float* Wc = (const float*)d_in[13];
  const float* bc = (const float*)d_in[14];
  const int* src = (const int*)d_in[15];
  const int* dst = (const int*)d_in[16];
  float* out = (float*)d_out;

  // ---- workspace layout: f32/u32 first (16B-aligned sizes), bf16 after ----
  float* el = (float*)d_ws;                                  // N*4
  float* er = el + (size_t)N_NODES * 4;                      // N*4
  float* denom = er + (size_t)N_NODES * 4;                   // N*4
  unsigned* emax = (unsigned*)(denom + (size_t)N_NODES * 4); // N*4
  float* eval = (float*)(emax + (size_t)N_NODES * 4);        // E*4
  float* hg = eval + (size_t)E_EDGES * 4;                    // 128
  unsigned* deg = (unsigned*)(hg + 128);                     // N
  unsigned* offv = deg + N_NODES;                            // N+1 (+3 pad)
  unsigned* cursor = offv + N_NODES + 4;                     // N
  int* csr_src = (int*)(cursor + N_NODES);                   // E
  int* csr_eid = csr_src + E_EDGES;                          // E
  unsigned short* featb = (unsigned short*)(csr_eid + E_EDGES); // N*512
  unsigned short* hbufb = featb + (size_t)N_NODES * HD;         // N*128
  unsigned short* xb = hbufb + (size_t)N_NODES * D_DIM;         // N*256
  unsigned short* WTb = xb + (size_t)N_NODES * 256;             // 512*256 max

  // ---- build CSR once (dst constant across layers) ----
  hipMemsetAsync(deg, 0, (size_t)N_NODES * sizeof(unsigned), stream);
  histo_kernel<<<(E_EDGES + 255) / 256, 256, 0, stream>>>(dst, deg);
  scan_kernel<<<1, 1024, 0, stream>>>(deg, offv, cursor);
  scatter_kernel<<<(E_EDGES + 255) / 256, 256, 0, stream>>>(src, dst, cursor, csr_src, csr_eid);

  // cast layer-1 input once
  cast_f2b<<<(N_NODES * 256 / 4 + 255) / 256, 256, 0, stream>>>(nfeats, xb, N_NODES * 256 / 4);

  auto run_layer = [&](const unsigned short* X, int K, const float* Wm, const float* alv,
                       const float* arv, const float* bv) {
    transpose_cast<<<(K * HD + 255) / 256, 256, 0, stream>>>(Wm, WTb, K);
    dim3 g((N_NODES + 63) / 64, HD / 128);
    gemm_mfma<<<g, 256, 0, stream>>>(X, WTb, featb, K);
    eler_kernel<<<N_NODES, 256, 0, stream>>>(featb, alv, arv, el, er);
    hipMemsetAsync(emax, 0, (size_t)N_NODES * 4 * sizeof(unsigned), stream);
    hipMemsetAsync(denom, 0, (size_t)N_NODES * 4 * sizeof(float), stream);
    edge_pass1<<<(E_EDGES + 255) / 256, 256, 0, stream>>>(src, dst, el, er, eval, emax);
    edge_pass2<<<(E_EDGES + 255) / 256, 256, 0, stream>>>(dst, eval, emax, denom);
    aggregate_csr<<<N_NODES, 64, 0, stream>>>(offv, csr_src, csr_eid, eval, denom, featb, bv, hbufb);
  };

  run_layer(xb, 256, W1, al1, ar1, b1);
  run_layer(hbufb, 128, W2, al2, ar2, b2);
  run_layer(hbufb, 128, W3, al3, ar3, b3);

  hipMemsetAsync(hg, 0, 128 * sizeof(float), stream);
  colsum<<<1024, 128, 0, stream>>>(hbufb, hg);
  final_k<<<1, 64, 0, stream>>>(hg, Wc, bc, out);
}

// Round 4
// 999.650 us; speedup vs baseline: 5.2569x; 1.8437x over previous
//
#include <hip/hip_runtime.h>
#include <hip/hip_bf16.h>

#define N_NODES 50000
#define E_EDGES 800000
#define HD 512
#define H_HEADS 4
#define D_DIM 128

typedef __attribute__((ext_vector_type(8))) short bf16x8;
typedef __attribute__((ext_vector_type(4))) float f32x4;

__device__ __forceinline__ unsigned short f2b(float f) {
  unsigned u = __float_as_uint(f);
  u += 0x7FFFu + ((u >> 16) & 1u);  // RNE
  return (unsigned short)(u >> 16);
}
__device__ __forceinline__ float b2f(unsigned short s) {
  return __uint_as_float(((unsigned)s) << 16);
}

// ---------------- cast f32 -> bf16, 4 elems/thread ----------------
__global__ void cast_f2b(const float* __restrict__ in, unsigned short* __restrict__ out, int n4) {
  int i = blockIdx.x * blockDim.x + threadIdx.x;
  if (i >= n4) return;
  float4 v = *(const float4*)(in + (size_t)i * 4);
  ushort4 o;
  o.x = f2b(v.x); o.y = f2b(v.y); o.z = f2b(v.z); o.w = f2b(v.w);
  *(ushort4*)(out + (size_t)i * 4) = o;
}

// ---------------- W[K,512] f32 -> WT[512,K] bf16 ----------------
__global__ void transpose_cast(const float* __restrict__ W, unsigned short* __restrict__ WT, int K) {
  int idx = blockIdx.x * blockDim.x + threadIdx.x;
  if (idx >= K * HD) return;
  int k = idx >> 9, c = idx & (HD - 1);
  WT[(size_t)c * K + k] = f2b(W[idx]);
}

// ---------------- MFMA GEMM: feat[N,512](bf16) = X[N,K](bf16) @ W ----------------
__global__ __launch_bounds__(256) void gemm_mfma(const unsigned short* __restrict__ X,
                                                 const unsigned short* __restrict__ WT,
                                                 unsigned short* __restrict__ feat, int K) {
  const int tid = threadIdx.x;
  const int w = tid >> 6, l = tid & 63;
  const int row0 = blockIdx.x * 64 + w * 16;
  const int col0 = blockIdx.y * 128;
  const int lr = l & 15;        // A-row / B-col within tile
  const int lk = (l >> 4) * 8;  // k-offset within 32
  f32x4 acc[8] = {};
  int arow = row0 + lr;
  if (arow >= N_NODES) arow = N_NODES - 1;  // clamp; stores guarded
  const unsigned short* aptr = X + (size_t)arow * K + lk;
  for (int k0 = 0; k0 < K; k0 += 32) {
    bf16x8 a = *(const bf16x8*)(aptr + k0);
#pragma unroll
    for (int c = 0; c < 8; ++c) {
      const unsigned short* bp = WT + (size_t)(col0 + c * 16 + lr) * K + k0 + lk;
      bf16x8 b = *(const bf16x8*)bp;
      acc[c] = __builtin_amdgcn_mfma_f32_16x16x32_bf16(a, b, acc[c], 0, 0, 0);
    }
  }
  const int orow = row0 + (l >> 4) * 4;
#pragma unroll
  for (int c = 0; c < 8; ++c) {
#pragma unroll
    for (int i = 0; i < 4; ++i) {
      int r = orow + i;
      if (r < N_NODES) feat[(size_t)r * HD + col0 + c * 16 + lr] = f2b(acc[c][i]);
    }
  }
}

// ---------------- el/er: wave per (node, head) ----------------
__global__ void eler_kernel(const unsigned short* __restrict__ feat, const float* __restrict__ al,
                            const float* __restrict__ ar, float* __restrict__ el,
                            float* __restrict__ er) {
  int n = blockIdx.x;
  int h = threadIdx.x >> 6;
  int lane = threadIdx.x & 63;
  const unsigned short* f = feat + (size_t)n * HD + h * D_DIM;
  const float* alh = al + h * D_DIM;
  const float* arh = ar + h * D_DIM;
  float f0 = b2f(f[lane]), f1 = b2f(f[lane + 64]);
  float sl = f0 * alh[lane] + f1 * alh[lane + 64];
  float sr = f0 * arh[lane] + f1 * arh[lane + 64];
#pragma unroll
  for (int off = 32; off >= 1; off >>= 1) {
    sl += __shfl_xor(sl, off);
    sr += __shfl_xor(sr, off);
  }
  if (lane == 0) {
    el[n * 4 + h] = sl;
    er[n * 4 + h] = sr;
  }
}

// ---------------- CSR build ----------------
__global__ void histo_kernel(const int* __restrict__ dst, unsigned* __restrict__ deg) {
  int e = blockIdx.x * blockDim.x + threadIdx.x;
  if (e >= E_EDGES) return;
  atomicAdd(&deg[dst[e]], 1u);
}

__global__ void scan_kernel(const unsigned* __restrict__ deg, unsigned* __restrict__ off,
                            unsigned* __restrict__ cursor) {
  __shared__ unsigned warp_sums[16];
  __shared__ unsigned carry_s;
  const int tid = threadIdx.x;  // 1024
  const int wid = tid >> 6;
  if (tid == 0) carry_s = 0;
  __syncthreads();
  for (int base = 0; base < N_NODES; base += 1024) {
    int i = base + tid;
    unsigned v = (i < N_NODES) ? deg[i] : 0u;
    unsigned x = v;
#pragma unroll
    for (int o = 1; o < 64; o <<= 1) {
      unsigned y = __shfl_up(x, o);
      if ((tid & 63) >= o) x += y;
    }
    if ((tid & 63) == 63) warp_sums[wid] = x;
    __syncthreads();
    if (tid < 16) {
      unsigned s = warp_sums[tid];
#pragma unroll
      for (int o = 1; o < 16; o <<= 1) {
        unsigned y = __shfl_up(s, o);
        if (tid >= o) s += y;
      }
      warp_sums[tid] = s;
    }
    __syncthreads();
    unsigned carry = carry_s;
    unsigned wprev = (wid > 0) ? warp_sums[wid - 1] : 0u;
    unsigned excl = carry + wprev + (x - v);
    if (i < N_NODES) {
      off[i] = excl;
      cursor[i] = excl;
    }
    __syncthreads();
    if (tid == 0) carry_s = carry + warp_sums[15];
    __syncthreads();
  }
  if (tid == 0) off[N_NODES] = carry_s;
}

__global__ void scatter_kernel(const int* __restrict__ src, const int* __restrict__ dst,
                               unsigned* __restrict__ cursor, int* __restrict__ csr_src) {
  int e = blockIdx.x * blockDim.x + threadIdx.x;
  if (e >= E_EDGES) return;
  int d = dst[e];
  unsigned pos = atomicAdd(&cursor[d], 1u);
  csr_src[pos] = src[e];
}

// ---------------- fused edge softmax (CSR, atomic-free): aw[j] = normalized weight ----------------
__global__ void edge_softmax_csr(const unsigned* __restrict__ off, const int* __restrict__ csr_src,
                                 const float* __restrict__ el, const float* __restrict__ er,
                                 float* __restrict__ aw) {
  const int n = blockIdx.x;
  const int l = threadIdx.x;  // 64
  const unsigned beg = off[n], end = off[n + 1];
  const int deg = (int)(end - beg);
  if (deg == 0) return;
  float4 rr = *(const float4*)(er + (size_t)n * 4);
  const float NEG = -3.0e38f;
  if (deg <= 64) {
    float v0 = NEG, v1 = NEG, v2 = NEG, v3 = NEG;
    if (l < deg) {
      int s = csr_src[beg + l];
      float4 ll = *(const float4*)(el + (size_t)s * 4);
      v0 = ll.x + rr.x; v0 = (v0 > 0.f) ? v0 : 0.2f * v0;
      v1 = ll.y + rr.y; v1 = (v1 > 0.f) ? v1 : 0.2f * v1;
      v2 = ll.z + rr.z; v2 = (v2 > 0.f) ? v2 : 0.2f * v2;
      v3 = ll.w + rr.w; v3 = (v3 > 0.f) ? v3 : 0.2f * v3;
    }
    float m0 = v0, m1 = v1, m2 = v2, m3 = v3;
#pragma unroll
    for (int o = 32; o >= 1; o >>= 1) {
      m0 = fmaxf(m0, __shfl_xor(m0, o));
      m1 = fmaxf(m1, __shfl_xor(m1, o));
      m2 = fmaxf(m2, __shfl_xor(m2, o));
      m3 = fmaxf(m3, __shfl_xor(m3, o));
    }
    float e0 = 0.f, e1 = 0.f, e2 = 0.f, e3 = 0.f;
    if (l < deg) {
      e0 = __expf(v0 - m0); e1 = __expf(v1 - m1);
      e2 = __expf(v2 - m2); e3 = __expf(v3 - m3);
    }
    float s0 = e0, s1 = e1, s2 = e2, s3 = e3;
#pragma unroll
    for (int o = 32; o >= 1; o >>= 1) {
      s0 += __shfl_xor(s0, o);
      s1 += __shfl_xor(s1, o);
      s2 += __shfl_xor(s2, o);
      s3 += __shfl_xor(s3, o);
    }
    if (l < deg) {
      float4 o4 = {e0 / s0, e1 / s1, e2 / s2, e3 / s3};
      *(float4*)(aw + (size_t)(beg + l) * 4) = o4;
    }
  } else {
    // generic 3-pass path
    float m0 = NEG, m1 = NEG, m2 = NEG, m3 = NEG;
    for (int j = l; j < deg; j += 64) {
      int s = csr_src[beg + j];
      float4 ll = *(const float4*)(el + (size_t)s * 4);
      float v0 = ll.x + rr.x; v0 = (v0 > 0.f) ? v0 : 0.2f * v0;
      float v1 = ll.y + rr.y; v1 = (v1 > 0.f) ? v1 : 0.2f * v1;
      float v2 = ll.z + rr.z; v2 = (v2 > 0.f) ? v2 : 0.2f * v2;
      float v3 = ll.w + rr.w; v3 = (v3 > 0.f) ? v3 : 0.2f * v3;
      float4 o4 = {v0, v1, v2, v3};
      *(float4*)(aw + (size_t)(beg + j) * 4) = o4;
      m0 = fmaxf(m0, v0); m1 = fmaxf(m1, v1);
      m2 = fmaxf(m2, v2); m3 = fmaxf(m3, v3);
    }
#pragma unroll
    for (int o = 32; o >= 1; o >>= 1) {
      m0 = fmaxf(m0, __shfl_xor(m0, o));
      m1 = fmaxf(m1, __shfl_xor(m1, o));
      m2 = fmaxf(m2, __shfl_xor(m2, o));
      m3 = fmaxf(m3, __shfl_xor(m3, o));
    }
    float s0 = 0.f, s1 = 0.f, s2 = 0.f, s3 = 0.f;
    for (int j = l; j < deg; j += 64) {
      float4 v = *(const float4*)(aw + (size_t)(beg + j) * 4);
      v.x = __expf(v.x - m0); v.y = __expf(v.y - m1);
      v.z = __expf(v.z - m2); v.w = __expf(v.w - m3);
      *(float4*)(aw + (size_t)(beg + j) * 4) = v;
      s0 += v.x; s1 += v.y; s2 += v.z; s3 += v.w;
    }
#pragma unroll
    for (int o = 32; o >= 1; o >>= 1) {
      s0 += __shfl_xor(s0, o);
      s1 += __shfl_xor(s1, o);
      s2 += __shfl_xor(s2, o);
      s3 += __shfl_xor(s3, o);
    }
    float i0 = 1.f / s0, i1 = 1.f / s1, i2 = 1.f / s2, i3 = 1.f / s3;
    for (int j = l; j < deg; j += 64) {
      float4 v = *(const float4*)(aw + (size_t)(beg + j) * 4);
      v.x *= i0; v.y *= i1; v.z *= i2; v.w *= i3;
      *(float4*)(aw + (size_t)(beg + j) * 4) = v;
    }
  }
}

// ---------------- CSR aggregate + bias + relu + head-mean -> bf16 hbuf ----------------
// 1 wave per node; thread t handles d = 2t, 2t+1 for all 4 heads
__global__ void aggregate_csr(const unsigned* __restrict__ off, const int* __restrict__ csr_src,
                              const float* __restrict__ aw,
                              const unsigned short* __restrict__ feat,
                              const float* __restrict__ bias, unsigned short* __restrict__ hbuf) {
  int n = blockIdx.x;
  int t = threadIdx.x;  // 64
  unsigned beg = off[n], end = off[n + 1];
  float acc[4][2] = {};
  for (unsigned j = beg; j < end; ++j) {
    int s = csr_src[j];
    float4 wv = *(const float4*)(aw + (size_t)j * 4);
    float w4[4] = {wv.x, wv.y, wv.z, wv.w};
    const unsigned short* f = feat + (size_t)s * HD + 2 * t;
#pragma unroll
    for (int h = 0; h < 4; ++h) {
      unsigned pk = *(const unsigned*)(f + h * D_DIM);
      acc[h][0] = fmaf(b2f((unsigned short)(pk & 0xFFFFu)), w4[h], acc[h][0]);
      acc[h][1] = fmaf(b2f((unsigned short)(pk >> 16)), w4[h], acc[h][1]);
    }
  }
  float r0 = 0.f, r1 = 0.f;
#pragma unroll
  for (int h = 0; h < 4; ++h) {
    r0 += fmaxf(acc[h][0] + bias[h * D_DIM + 2 * t], 0.f);
    r1 += fmaxf(acc[h][1] + bias[h * D_DIM + 2 * t + 1], 0.f);
  }
  ushort2 o;
  o.x = f2b(r0 * 0.25f);
  o.y = f2b(r1 * 0.25f);
  *(ushort2*)(hbuf + (size_t)n * D_DIM + 2 * t) = o;
}

// ---------------- readout ----------------
__global__ void colsum(const unsigned short* __restrict__ hbuf, float* __restrict__ hg) {
  int d = threadIdx.x;  // 128
  float s = 0.0f;
  for (int n = blockIdx.x; n < N_NODES; n += gridDim.x)
    s += b2f(hbuf[(size_t)n * D_DIM + d]);
  atomicAdd(&hg[d], s);
}

__global__ void final_k(const float* __restrict__ hg, const float* __restrict__ Wc,
                        const float* __restrict__ bc, float* __restrict__ out) {
  int l = threadIdx.x;  // 64
  float v = hg[l] * Wc[l] + hg[l + 64] * Wc[l + 64];
#pragma unroll
  for (int off = 32; off >= 1; off >>= 1) v += __shfl_xor(v, off);
  if (l == 0) {
    float x = v * (1.0f / N_NODES) + bc[0];
    out[0] = 1.0f / (1.0f + expf(-x));
  }
}

extern "C" void kernel_launch(void* const* d_in, const int* in_sizes, int n_in,
                              void* d_out, int out_size, void* d_ws, size_t ws_size,
                              hipStream_t stream) {
  const float* nfeats = (const float*)d_in[0];
  const float* W1 = (const float*)d_in[1];
  const float* al1 = (const float*)d_in[2];
  const float* ar1 = (const float*)d_in[3];
  const float* b1 = (const float*)d_in[4];
  const float* W2 = (const float*)d_in[5];
  const float* al2 = (const float*)d_in[6];
  const float* ar2 = (const float*)d_in[7];
  const float* b2 = (const float*)d_in[8];
  const float* W3 = (const float*)d_in[9];
  const float* al3 = (const float*)d_in[10];
  const float* ar3 = (const float*)d_in[11];
  const float* b3 = (const float*)d_in[12];
  const float* Wc = (const float*)d_in[13];
  const float* bc = (const float*)d_in[14];
  const int* src = (const int*)d_in[15];
  const int* dst = (const int*)d_in[16];
  float* out = (float*)d_out;

  // ---- workspace layout: f32/u32 first, bf16 after ----
  float* el = (float*)d_ws;                                  // N*4
  float* er = el + (size_t)N_NODES * 4;                      // N*4
  float* aw = er + (size_t)N_NODES * 4;                      // E*4 (CSR-ordered)
  float* hg = aw + (size_t)E_EDGES * 4;                      // 128
  unsigned* deg = (unsigned*)(hg + 128);                     // N
  unsigned* offv = deg + N_NODES;                            // N+1 (+3 pad)
  unsigned* cursor = offv + N_NODES + 4;                     // N
  int* csr_src = (int*)(cursor + N_NODES);                   // E
  unsigned short* featb = (unsigned short*)(csr_src + E_EDGES); // N*512
  unsigned short* hbufb = featb + (size_t)N_NODES * HD;         // N*128
  unsigned short* xb = hbufb + (size_t)N_NODES * D_DIM;         // N*256
  unsigned short* WTb = xb + (size_t)N_NODES * 256;             // 512*256 max

  // ---- build CSR once (dst constant across layers) ----
  hipMemsetAsync(deg, 0, (size_t)N_NODES * sizeof(unsigned), stream);
  histo_kernel<<<(E_EDGES + 255) / 256, 256, 0, stream>>>(dst, deg);
  scan_kernel<<<1, 1024, 0, stream>>>(deg, offv, cursor);
  scatter_kernel<<<(E_EDGES + 255) / 256, 256, 0, stream>>>(src, dst, cursor, csr_src);

  // cast layer-1 input once
  cast_f2b<<<(N_NODES * 256 / 4 + 255) / 256, 256, 0, stream>>>(nfeats, xb, N_NODES * 256 / 4);

  auto run_layer = [&](const unsigned short* X, int K, const float* Wm, const float* alv,
                       const float* arv, const float* bv) {
    transpose_cast<<<(K * HD + 255) / 256, 256, 0, stream>>>(Wm, WTb, K);
    dim3 g((N_NODES + 63) / 64, HD / 128);
    gemm_mfma<<<g, 256, 0, stream>>>(X, WTb, featb, K);
    eler_kernel<<<N_NODES, 256, 0, stream>>>(featb, alv, arv, el, er);
    edge_softmax_csr<<<N_NODES, 64, 0, stream>>>(offv, csr_src, el, er, aw);
    aggregate_csr<<<N_NODES, 64, 0, stream>>>(offv, csr_src, aw, featb, bv, hbufb);
  };

  run_layer(xb, 256, W1, al1, ar1, b1);
  run_layer(hbufb, 128, W2, al2, ar2, b2);
  run_layer(hbufb, 128, W3, al3, ar3, b3);

  hipMemsetAsync(hg, 0, 128 * sizeof(float), stream);
  colsum<<<1024, 128, 0, stream>>>(hbufb, hg);
  final_k<<<1, 64, 0, stream>>>(hg, Wc, bc, out);
}

// Round 6
// 646.099 us; speedup vs baseline: 8.1336x; 1.5472x over previous
//
#include <hip/hip_runtime.h>
#include <hip/hip_bf16.h>

#define N_NODES 50000
#define E_EDGES 800000
#define HD 512
#define H_HEADS 4
#define D_DIM 128
#define N_PAD 53248  // 13 * 4096, zero-padded degree array for vectorized scan

typedef __attribute__((ext_vector_type(8))) short bf16x8;
typedef __attribute__((ext_vector_type(4))) float f32x4;
typedef __attribute__((ext_vector_type(2))) float f32x2;

__device__ __forceinline__ unsigned short f2b(float f) {
  unsigned u = __float_as_uint(f);
  u += 0x7FFFu + ((u >> 16) & 1u);  // RNE
  return (unsigned short)(u >> 16);
}
__device__ __forceinline__ float b2f(unsigned short s) {
  return __uint_as_float(((unsigned)s) << 16);
}
__device__ __forceinline__ float lrelu(float v) { return v > 0.f ? v : 0.2f * v; }
__device__ __forceinline__ float sel4(float a, float b, float c, float d, int h) {
  return h == 0 ? a : (h == 1 ? b : (h == 2 ? c : d));
}

// ---------------- cast f32 -> bf16, 4 elems/thread ----------------
__global__ void cast_f2b(const float* __restrict__ in, unsigned short* __restrict__ out, int n4) {
  int i = blockIdx.x * blockDim.x + threadIdx.x;
  if (i >= n4) return;
  float4 v = *(const float4*)(in + (size_t)i * 4);
  ushort4 o;
  o.x = f2b(v.x); o.y = f2b(v.y); o.z = f2b(v.z); o.w = f2b(v.w);
  *(ushort4*)(out + (size_t)i * 4) = o;
}

// ---------------- W[K,512] f32 -> WT[512,K] bf16 ----------------
__global__ void transpose_cast(const float* __restrict__ W, unsigned short* __restrict__ WT, int K) {
  int idx = blockIdx.x * blockDim.x + threadIdx.x;
  if (idx >= K * HD) return;
  int k = idx >> 9, c = idx & (HD - 1);
  WT[(size_t)c * K + k] = f2b(W[idx]);
}

// ---------------- MFMA GEMM: feat[N,512](bf16) = X[N,K](bf16) @ W ----------------
__global__ __launch_bounds__(256) void gemm_mfma(const unsigned short* __restrict__ X,
                                                 const unsigned short* __restrict__ WT,
                                                 unsigned short* __restrict__ feat, int K) {
  const int tid = threadIdx.x;
  const int w = tid >> 6, l = tid & 63;
  const int row0 = blockIdx.x * 64 + w * 16;
  const int col0 = blockIdx.y * 128;
  const int lr = l & 15;        // A-row / B-col within tile
  const int lk = (l >> 4) * 8;  // k-offset within 32
  f32x4 acc[8] = {};
  int arow = row0 + lr;
  if (arow >= N_NODES) arow = N_NODES - 1;  // clamp; stores guarded
  const unsigned short* aptr = X + (size_t)arow * K + lk;
  for (int k0 = 0; k0 < K; k0 += 32) {
    bf16x8 a = *(const bf16x8*)(aptr + k0);
#pragma unroll
    for (int c = 0; c < 8; ++c) {
      const unsigned short* bp = WT + (size_t)(col0 + c * 16 + lr) * K + k0 + lk;
      bf16x8 b = *(const bf16x8*)bp;
      acc[c] = __builtin_amdgcn_mfma_f32_16x16x32_bf16(a, b, acc[c], 0, 0, 0);
    }
  }
  const int orow = row0 + (l >> 4) * 4;
#pragma unroll
  for (int c = 0; c < 8; ++c) {
#pragma unroll
    for (int i = 0; i < 4; ++i) {
      int r = orow + i;
      if (r < N_NODES) feat[(size_t)r * HD + col0 + c * 16 + lr] = f2b(acc[c][i]);
    }
  }
}

// ---------------- fused el/er + fp8 cast: 1 wave per node ----------------
// thread t: head h = t>>4, dims d0=(t&15)*8 .. +7
__global__ __launch_bounds__(64) void eler_cast(const unsigned short* __restrict__ feat,
                                                const float* __restrict__ al,
                                                const float* __restrict__ ar,
                                                float* __restrict__ el, float* __restrict__ er,
                                                unsigned char* __restrict__ featq) {
  const int n = blockIdx.x, t = threadIdx.x;  // 64
  const int h = t >> 4, d0 = (t & 15) * 8;
  uint4 raw = *(const uint4*)(feat + (size_t)n * HD + t * 8);
  unsigned rw[4] = {raw.x, raw.y, raw.z, raw.w};
  float fv[8];
#pragma unroll
  for (int i = 0; i < 4; ++i) {
    fv[2 * i] = b2f((unsigned short)(rw[i] & 0xFFFFu));
    fv[2 * i + 1] = b2f((unsigned short)(rw[i] >> 16));
  }
  const float* alh = al + h * D_DIM + d0;
  const float* arh = ar + h * D_DIM + d0;
  float4 a0 = *(const float4*)alh, a1 = *(const float4*)(alh + 4);
  float4 r0 = *(const float4*)arh, r1 = *(const float4*)(arh + 4);
  float av[8] = {a0.x, a0.y, a0.z, a0.w, a1.x, a1.y, a1.z, a1.w};
  float rv[8] = {r0.x, r0.y, r0.z, r0.w, r1.x, r1.y, r1.z, r1.w};
  float sl = 0.f, sr = 0.f;
#pragma unroll
  for (int i = 0; i < 8; ++i) {
    sl = fmaf(fv[i], av[i], sl);
    sr = fmaf(fv[i], rv[i], sr);
  }
#pragma unroll
  for (int o = 1; o < 16; o <<= 1) {
    sl += __shfl_xor(sl, o);
    sr += __shfl_xor(sr, o);
  }
  if ((t & 15) == 0) {
    el[n * 4 + h] = sl;
    er[n * 4 + h] = sr;
  }
  // fp8 pack (HW converter; encode/decode use same format so roundtrip is consistent)
  int q0 = __builtin_amdgcn_cvt_pk_fp8_f32(fv[0], fv[1], 0, false);
  q0 = __builtin_amdgcn_cvt_pk_fp8_f32(fv[2], fv[3], q0, true);
  int q1 = __builtin_amdgcn_cvt_pk_fp8_f32(fv[4], fv[5], 0, false);
  q1 = __builtin_amdgcn_cvt_pk_fp8_f32(fv[6], fv[7], q1, true);
  uint2 qq;
  qq.x = (unsigned)q0;
  qq.y = (unsigned)q1;
  *(uint2*)(featq + (size_t)n * HD + t * 8) = qq;
}

// ---------------- CSR build ----------------
__global__ void histo_kernel(const int* __restrict__ dst, unsigned* __restrict__ deg) {
  int e = blockIdx.x * blockDim.x + threadIdx.x;
  if (e >= E_EDGES) return;
  atomicAdd(&deg[dst[e]], 1u);
}

// single-workgroup exclusive scan, 4 elems/thread (deg zero-padded to N_PAD)
__global__ void scan_kernel(const unsigned* __restrict__ deg, unsigned* __restrict__ off,
                            unsigned* __restrict__ cursor) {
  __shared__ unsigned warp_sums[16];
  __shared__ unsigned carry_s;
  const int tid = threadIdx.x;  // 1024
  const int wid = tid >> 6;
  if (tid == 0) carry_s = 0;
  __syncthreads();
  for (int base = 0; base < N_PAD; base += 4096) {
    int i = base + tid * 4;
    uint4 v = *(const uint4*)(deg + i);
    unsigned sm = v.x + v.y + v.z + v.w;
    unsigned x = sm;
#pragma unroll
    for (int o = 1; o < 64; o <<= 1) {
      unsigned y = __shfl_up(x, o);
      if ((tid & 63) >= o) x += y;
    }
    if ((tid & 63) == 63) warp_sums[wid] = x;
    __syncthreads();
    if (tid < 16) {
      unsigned s = warp_sums[tid];
#pragma unroll
      for (int o = 1; o < 16; o <<= 1) {
        unsigned y = __shfl_up(s, o);
        if (tid >= o) s += y;
      }
      warp_sums[tid] = s;
    }
    __syncthreads();
    unsigned carry = carry_s;
    unsigned wprev = (wid > 0) ? warp_sums[wid - 1] : 0u;
    unsigned ex = carry + wprev + (x - sm);
    uint4 o4;
    o4.x = ex;
    o4.y = ex + v.x;
    o4.z = o4.y + v.y;
    o4.w = o4.z + v.z;
    *(uint4*)(off + i) = o4;
    *(uint4*)(cursor + i) = o4;
    __syncthreads();
    if (tid == 0) carry_s = carry + warp_sums[15];
    __syncthreads();
  }
}

__global__ void scatter_kernel(const int* __restrict__ src, const int* __restrict__ dst,
                               unsigned* __restrict__ cursor, int* __restrict__ csr_src) {
  int e = blockIdx.x * blockDim.x + threadIdx.x;
  if (e >= E_EDGES) return;
  int d = dst[e];
  unsigned pos = atomicAdd(&cursor[d], 1u);
  csr_src[pos] = src[e];
}

// ---------------- fused edge-softmax + aggregate + bias/relu/head-mean ----------------
// 1 wave per node. thread t: head h=t>>4, dims d0=(t&15)*8 .. +7 (fp8 gather, 8B/thread)
__global__ __launch_bounds__(64) void agg_fused(const unsigned* __restrict__ off,
                                                const int* __restrict__ csr_src,
                                                const float* __restrict__ el,
                                                const float* __restrict__ er,
                                                const unsigned char* __restrict__ featq,
                                                const float* __restrict__ bias,
                                                unsigned short* __restrict__ hbuf) {
  __shared__ float4 ws4[64];
  const int n = blockIdx.x, t = threadIdx.x;
  const int h = t >> 4, d0 = (t & 15) * 8;
  const unsigned beg = off[n];
  const int deg = (int)(off[n + 1] - beg);
  const float NEG = -3.0e38f;
  float4 rr = *(const float4*)(er + (size_t)n * 4);
  float acc[8] = {};

  if (deg <= 64) {
    float4 v = {NEG, NEG, NEG, NEG};
    if (t < deg) {
      int s = csr_src[beg + t];
      float4 ll = *(const float4*)(el + (size_t)s * 4);
      v.x = lrelu(ll.x + rr.x);
      v.y = lrelu(ll.y + rr.y);
      v.z = lrelu(ll.z + rr.z);
      v.w = lrelu(ll.w + rr.w);
    }
    float m0 = v.x, m1 = v.y, m2 = v.z, m3 = v.w;
#pragma unroll
    for (int o = 32; o >= 1; o >>= 1) {
      m0 = fmaxf(m0, __shfl_xor(m0, o));
      m1 = fmaxf(m1, __shfl_xor(m1, o));
      m2 = fmaxf(m2, __shfl_xor(m2, o));
      m3 = fmaxf(m3, __shfl_xor(m3, o));
    }
    float4 ev = {0.f, 0.f, 0.f, 0.f};
    if (t < deg) {
      ev.x = __expf(v.x - m0);
      ev.y = __expf(v.y - m1);
      ev.z = __expf(v.z - m2);
      ev.w = __expf(v.w - m3);
    }
    float s0 = ev.x, s1 = ev.y, s2 = ev.z, s3 = ev.w;
#pragma unroll
    for (int o = 32; o >= 1; o >>= 1) {
      s0 += __shfl_xor(s0, o);
      s1 += __shfl_xor(s1, o);
      s2 += __shfl_xor(s2, o);
      s3 += __shfl_xor(s3, o);
    }
    if (t < deg) ws4[t] = ev;
    float invh = 1.0f / sel4(s0, s1, s2, s3, h);
    __syncthreads();
    int sj = (deg > 0) ? csr_src[beg] : 0;
    for (int j = 0; j < deg; ++j) {
      int sn = csr_src[beg + ((j + 1 < deg) ? j + 1 : j)];
      float4 wv = ws4[j];
      float w = sel4(wv.x, wv.y, wv.z, wv.w, h) * invh;
      uint2 q = *(const uint2*)(featq + (size_t)sj * HD + t * 8);
      f32x2 p0 = __builtin_amdgcn_cvt_pk_f32_fp8((int)q.x, false);
      f32x2 p1 = __builtin_amdgcn_cvt_pk_f32_fp8((int)q.x, true);
      f32x2 p2 = __builtin_amdgcn_cvt_pk_f32_fp8((int)q.y, false);
      f32x2 p3 = __builtin_amdgcn_cvt_pk_f32_fp8((int)q.y, true);
      acc[0] = fmaf(p0[0], w, acc[0]);
      acc[1] = fmaf(p0[1], w, acc[1]);
      acc[2] = fmaf(p1[0], w, acc[2]);
      acc[3] = fmaf(p1[1], w, acc[3]);
      acc[4] = fmaf(p2[0], w, acc[4]);
      acc[5] = fmaf(p2[1], w, acc[5]);
      acc[6] = fmaf(p3[0], w, acc[6]);
      acc[7] = fmaf(p3[1], w, acc[7]);
      sj = sn;
    }
  } else {
    // rare: 3-pass recompute path, correct for any degree
    float m[4] = {NEG, NEG, NEG, NEG};
    for (int j = t; j < deg; j += 64) {
      int s = csr_src[beg + j];
      float4 ll = *(const float4*)(el + (size_t)s * 4);
      m[0] = fmaxf(m[0], lrelu(ll.x + rr.x));
      m[1] = fmaxf(m[1], lrelu(ll.y + rr.y));
      m[2] = fmaxf(m[2], lrelu(ll.z + rr.z));
      m[3] = fmaxf(m[3], lrelu(ll.w + rr.w));
    }
#pragma unroll
    for (int o = 32; o >= 1; o >>= 1) {
      m[0] = fmaxf(m[0], __shfl_xor(m[0], o));
      m[1] = fmaxf(m[1], __shfl_xor(m[1], o));
      m[2] = fmaxf(m[2], __shfl_xor(m[2], o));
      m[3] = fmaxf(m[3], __shfl_xor(m[3], o));
    }
    float sm[4] = {0.f, 0.f, 0.f, 0.f};
    for (int j = t; j < deg; j += 64) {
      int s = csr_src[beg + j];
      float4 ll = *(const float4*)(el + (size_t)s * 4);
      sm[0] += __expf(lrelu(ll.x + rr.x) - m[0]);
      sm[1] += __expf(lrelu(ll.y + rr.y) - m[1]);
      sm[2] += __expf(lrelu(ll.z + rr.z) - m[2]);
      sm[3] += __expf(lrelu(ll.w + rr.w) - m[3]);
    }
#pragma unroll
    for (int o = 32; o >= 1; o >>= 1) {
      sm[0] += __shfl_xor(sm[0], o);
      sm[1] += __shfl_xor(sm[1], o);
      sm[2] += __shfl_xor(sm[2], o);
      sm[3] += __shfl_xor(sm[3], o);
    }
    float mh = sel4(m[0], m[1], m[2], m[3], h);
    float ih = 1.0f / sel4(sm[0], sm[1], sm[2], sm[3], h);
    float rrh = sel4(rr.x, rr.y, rr.z, rr.w, h);
    for (int j = 0; j < deg; ++j) {
      int sj = csr_src[beg + j];
      float llh = el[(size_t)sj * 4 + h];
      float w = __expf(lrelu(llh + rrh) - mh) * ih;
      uint2 q = *(const uint2*)(featq + (size_t)sj * HD + t * 8);
      f32x2 p0 = __builtin_amdgcn_cvt_pk_f32_fp8((int)q.x, false);
      f32x2 p1 = __builtin_amdgcn_cvt_pk_f32_fp8((int)q.x, true);
      f32x2 p2 = __builtin_amdgcn_cvt_pk_f32_fp8((int)q.y, false);
      f32x2 p3 = __builtin_amdgcn_cvt_pk_f32_fp8((int)q.y, true);
      acc[0] = fmaf(p0[0], w, acc[0]);
      acc[1] = fmaf(p0[1], w, acc[1]);
      acc[2] = fmaf(p1[0], w, acc[2]);
      acc[3] = fmaf(p1[1], w, acc[3]);
      acc[4] = fmaf(p2[0], w, acc[4]);
      acc[5] = fmaf(p2[1], w, acc[5]);
      acc[6] = fmaf(p3[0], w, acc[6]);
      acc[7] = fmaf(p3[1], w, acc[7]);
    }
  }

  // epilogue: +bias, relu, mean over heads (lanes t, t^16, t^32, t^48 share d-range)
  const float* bp = bias + h * D_DIM + d0;
  float4 b0 = *(const float4*)bp, b1 = *(const float4*)(bp + 4);
  float bv[8] = {b0.x, b0.y, b0.z, b0.w, b1.x, b1.y, b1.z, b1.w};
  float r[8];
#pragma unroll
  for (int i = 0; i < 8; ++i) r[i] = fmaxf(acc[i] + bv[i], 0.f);
#pragma unroll
  for (int i = 0; i < 8; ++i) {
    r[i] += __shfl_xor(r[i], 16);
    r[i] += __shfl_xor(r[i], 32);
  }
  if (h == 0) {
    uint4 o;
    o.x = (unsigned)f2b(r[0] * 0.25f) | ((unsigned)f2b(r[1] * 0.25f) << 16);
    o.y = (unsigned)f2b(r[2] * 0.25f) | ((unsigned)f2b(r[3] * 0.25f) << 16);
    o.z = (unsigned)f2b(r[4] * 0.25f) | ((unsigned)f2b(r[5] * 0.25f) << 16);
    o.w = (unsigned)f2b(r[6] * 0.25f) | ((unsigned)f2b(r[7] * 0.25f) << 16);
    *(uint4*)(hbuf + (size_t)n * D_DIM + d0) = o;
  }
}

// ---------------- readout ----------------
__global__ void colsum(const unsigned short* __restrict__ hbuf, float* __restrict__ hg) {
  int d = threadIdx.x;  // 128
  float s = 0.0f;
  for (int n = blockIdx.x; n < N_NODES; n += gridDim.x)
    s += b2f(hbuf[(size_t)n * D_DIM + d]);
  atomicAdd(&hg[d], s);
}

__global__ void final_k(const float* __restrict__ hg, const float* __restrict__ Wc,
                        const float* __restrict__ bc, float* __restrict__ out) {
  int l = threadIdx.x;  // 64
  float v = hg[l] * Wc[l] + hg[l + 64] * Wc[l + 64];
#pragma unroll
  for (int off = 32; off >= 1; off >>= 1) v += __shfl_xor(v, off);
  if (l == 0) {
    float x = v * (1.0f / N_NODES) + bc[0];
    out[0] = 1.0f / (1.0f + expf(-x));
  }
}

extern "C" void kernel_launch(void* const* d_in, const int* in_sizes, int n_in,
                              void* d_out, int out_size, void* d_ws, size_t ws_size,
                              hipStream_t stream) {
  const float* nfeats = (const float*)d_in[0];
  const float* W1 = (const float*)d_in[1];
  const float* al1 = (const float*)d_in[2];
  const float* ar1 = (const float*)d_in[3];
  const float* b1 = (const float*)d_in[4];
  const float* W2 = (const float*)d_in[5];
  const float* al2 = (const float*)d_in[6];
  const float* ar2 = (const float*)d_in[7];
  const float* b2 = (const float*)d_in[8];
  const float* W3 = (const float*)d_in[9];
  const float* al3 = (const float*)d_in[10];
  const float* ar3 = (const float*)d_in[11];
  const float* b3 = (const float*)d_in[12];
  const float* Wc = (const float*)d_in[13];
  const float* bc = (const float*)d_in[14];
  const int* src = (const int*)d_in[15];
  const int* dst = (const int*)d_in[16];
  float* out = (float*)d_out;

  // ---- workspace carve (256B aligned regions) ----
  char* p = (char*)d_ws;
  auto carve = [&](size_t bytes) {
    char* r = p;
    p += (bytes + 255) & ~(size_t)255;
    return r;
  };
  float* el = (float*)carve((size_t)N_NODES * 4 * 4);
  float* er = (float*)carve((size_t)N_NODES * 4 * 4);
  float* hg = (float*)carve(512);
  unsigned* deg = (unsigned*)carve((size_t)N_PAD * 4);
  unsigned* offv = (unsigned*)carve((size_t)(N_PAD + 4) * 4);
  unsigned* cursor = (unsigned*)carve((size_t)N_PAD * 4);
  int* csr_src = (int*)carve((size_t)E_EDGES * 4);
  unsigned short* featb = (unsigned short*)carve((size_t)N_NODES * HD * 2);
  unsigned char* featq = (unsigned char*)carve((size_t)N_NODES * HD);
  unsigned short* hbufb = (unsigned short*)carve((size_t)N_NODES * D_DIM * 2);
  unsigned short* xb = (unsigned short*)carve((size_t)N_NODES * 256 * 2);
  unsigned short* WT1 = (unsigned short*)carve((size_t)HD * 256 * 2);
  unsigned short* WT2 = (unsigned short*)carve((size_t)HD * 128 * 2);
  unsigned short* WT3 = (unsigned short*)carve((size_t)HD * 128 * 2);

  // ---- build CSR once (dst constant across layers) ----
  hipMemsetAsync(deg, 0, (size_t)N_PAD * sizeof(unsigned), stream);
  histo_kernel<<<(E_EDGES + 255) / 256, 256, 0, stream>>>(dst, deg);
  scan_kernel<<<1, 1024, 0, stream>>>(deg, offv, cursor);
  scatter_kernel<<<(E_EDGES + 255) / 256, 256, 0, stream>>>(src, dst, cursor, csr_src);

  // input cast + all weight transposes up front
  cast_f2b<<<(N_NODES * 256 / 4 + 255) / 256, 256, 0, stream>>>(nfeats, xb, N_NODES * 256 / 4);
  transpose_cast<<<(256 * HD + 255) / 256, 256, 0, stream>>>(W1, WT1, 256);
  transpose_cast<<<(128 * HD + 255) / 256, 256, 0, stream>>>(W2, WT2, 128);
  transpose_cast<<<(128 * HD + 255) / 256, 256, 0, stream>>>(W3, WT3, 128);

  auto run_layer = [&](const unsigned short* X, int K, const unsigned short* WT,
                       const float* alv, const float* arv, const float* bv) {
    dim3 g((N_NODES + 63) / 64, HD / 128);
    gemm_mfma<<<g, 256, 0, stream>>>(X, WT, featb, K);
    eler_cast<<<N_NODES, 64, 0, stream>>>(featb, alv, arv, el, er, featq);
    agg_fused<<<N_NODES, 64, 0, stream>>>(offv, csr_src, el, er, featq, bv, hbufb);
  };

  run_layer(xb, 256, WT1, al1, ar1, b1);
  run_layer(hbufb, 128, WT2, al2, ar2, b2);
  run_layer(hbufb, 128, WT3, al3, ar3, b3);

  hipMemsetAsync(hg, 0, 512, stream);
  colsum<<<1024, 128, 0, stream>>>(hbufb, hg);
  final_k<<<1, 64, 0, stream>>>(hg, Wc, bc, out);
}

// Round 7
// 491.925 us; speedup vs baseline: 10.6827x; 1.3134x over previous
//
#include <hip/hip_runtime.h>
#include <hip/hip_bf16.h>

#define N_NODES 50000
#define E_EDGES 800000
#define HD 512
#define H_HEADS 4
#define D_DIM 128
#define N_PAD 53248  // 13 * 4096, zero-padded degree array for vectorized scan

typedef __attribute__((ext_vector_type(8))) short bf16x8;
typedef __attribute__((ext_vector_type(4))) float f32x4;
typedef __attribute__((ext_vector_type(2))) float f32x2;

__device__ __forceinline__ unsigned short f2b(float f) {
  unsigned u = __float_as_uint(f);
  u += 0x7FFFu + ((u >> 16) & 1u);  // RNE
  return (unsigned short)(u >> 16);
}
__device__ __forceinline__ float b2f(unsigned short s) {
  return __uint_as_float(((unsigned)s) << 16);
}
__device__ __forceinline__ float lrelu(float v) { return v > 0.f ? v : 0.2f * v; }
__device__ __forceinline__ float sel4(float a, float b, float c, float d, int h) {
  return h == 0 ? a : (h == 1 ? b : (h == 2 ? c : d));
}

#define GLOAD_LDS16(g, l)                                             \
  __builtin_amdgcn_global_load_lds(                                   \
      (const __attribute__((address_space(1))) void*)(g),             \
      (__attribute__((address_space(3))) void*)(l), 16, 0, 0)

// ---------------- cast f32 -> bf16, 4 elems/thread ----------------
__global__ void cast_f2b(const float* __restrict__ in, unsigned short* __restrict__ out, int n4) {
  int i = blockIdx.x * blockDim.x + threadIdx.x;
  if (i >= n4) return;
  float4 v = *(const float4*)(in + (size_t)i * 4);
  ushort4 o;
  o.x = f2b(v.x); o.y = f2b(v.y); o.z = f2b(v.z); o.w = f2b(v.w);
  *(ushort4*)(out + (size_t)i * 4) = o;
}

// ---------------- W[K,512] f32 -> WT[512,K] bf16 ----------------
__global__ void transpose_cast(const float* __restrict__ W, unsigned short* __restrict__ WT, int K) {
  int idx = blockIdx.x * blockDim.x + threadIdx.x;
  if (idx >= K * HD) return;
  int k = idx >> 9, c = idx & (HD - 1);
  WT[(size_t)c * K + k] = f2b(W[idx]);
}

// ---------------- LDS-tiled MFMA GEMM: feat[N,512](bf16) = X[N,K](bf16) @ W ----------------
// BM=128, BN=128, BK=64; 4 waves (2x2), wave computes 64x64 (4x4 16x16x32 frags).
// LDS tiles stored [row][64k] with XOR swizzle byte ^= (row&7)<<4, applied via
// inverse-swizzled GLOBAL source (global_load_lds writes linearly) + swizzled ds_read.
__global__ __launch_bounds__(256) void gemm_mfma(const unsigned short* __restrict__ X,
                                                 const unsigned short* __restrict__ WT,
                                                 unsigned short* __restrict__ feat, int K) {
  __shared__ unsigned short Atile[128 * 64];
  __shared__ unsigned short Btile[128 * 64];
  const int tid = threadIdx.x;
  const int w = tid >> 6, l = tid & 63;
  const int wr = w >> 1, wc = w & 1;
  const int row0 = blockIdx.x * 128;
  const int col0 = blockIdx.y * 128;
  const int fr = l & 15;         // row/col within 16-frag
  const int fk = (l >> 4) * 8;   // k-element offset within 32
  f32x4 acc[4][4] = {};

  for (int k0 = 0; k0 < K; k0 += 64) {
    // ---- stage A and B tiles: 4 chunks of 256 threads x 16B each ----
#pragma unroll
    for (int j = 0; j < 4; ++j) {
      int idx = j * 256 + tid;                       // [0,1024): 16B chunk id
      int row = idx >> 3;                            // [0,128)
      int ksw = ((idx & 7) << 3) ^ ((row & 7) << 3); // inverse-swizzled k element
      int arow = row0 + row;
      if (arow >= N_NODES) arow = N_NODES - 1;       // clamp (stores guarded)
      GLOAD_LDS16(X + (size_t)arow * K + k0 + ksw,
                  (char*)Atile + j * 4096 + w * 1024);
      GLOAD_LDS16(WT + (size_t)(col0 + row) * K + k0 + ksw,
                  (char*)Btile + j * 4096 + w * 1024);
    }
    __syncthreads();
    // ---- compute: 2 k-sub-steps of 32 ----
#pragma unroll
    for (int kk = 0; kk < 64; kk += 32) {
      const int kel2 = (kk + fk) * 2;  // byte offset of k within row (multiple of 16)
      bf16x8 af[4], bf[4];
#pragma unroll
      for (int m = 0; m < 4; ++m) {
        int arow = wr * 64 + m * 16 + fr;
        af[m] = *(const bf16x8*)((const char*)Atile + arow * 128 + (kel2 ^ ((arow & 7) << 4)));
        int bcol = wc * 64 + m * 16 + fr;
        bf[m] = *(const bf16x8*)((const char*)Btile + bcol * 128 + (kel2 ^ ((bcol & 7) << 4)));
      }
#pragma unroll
      for (int m = 0; m < 4; ++m)
#pragma unroll
        for (int n = 0; n < 4; ++n)
          acc[m][n] = __builtin_amdgcn_mfma_f32_16x16x32_bf16(af[m], bf[n], acc[m][n], 0, 0, 0);
    }
    __syncthreads();
  }

  // ---- store: D mapping col=l&15, row=(l>>4)*4+i ----
  const int orow = row0 + wr * 64 + (l >> 4) * 4;
#pragma unroll
  for (int m = 0; m < 4; ++m) {
#pragma unroll
    for (int i = 0; i < 4; ++i) {
      int r = orow + m * 16 + i;
      if (r < N_NODES) {
#pragma unroll
        for (int n = 0; n < 4; ++n)
          feat[(size_t)r * HD + col0 + wc * 64 + n * 16 + fr] = f2b(acc[m][n][i]);
      }
    }
  }
}

// ---------------- fused el/er + fp8 cast: 1 wave per node ----------------
// thread t: head h = t>>4, dims d0=(t&15)*8 .. +7
__global__ __launch_bounds__(64) void eler_cast(const unsigned short* __restrict__ feat,
                                                const float* __restrict__ al,
                                                const float* __restrict__ ar,
                                                float* __restrict__ el, float* __restrict__ er,
                                                unsigned char* __restrict__ featq) {
  const int n = blockIdx.x, t = threadIdx.x;  // 64
  const int h = t >> 4, d0 = (t & 15) * 8;
  uint4 raw = *(const uint4*)(feat + (size_t)n * HD + t * 8);
  unsigned rw[4] = {raw.x, raw.y, raw.z, raw.w};
  float fv[8];
#pragma unroll
  for (int i = 0; i < 4; ++i) {
    fv[2 * i] = b2f((unsigned short)(rw[i] & 0xFFFFu));
    fv[2 * i + 1] = b2f((unsigned short)(rw[i] >> 16));
  }
  const float* alh = al + h * D_DIM + d0;
  const float* arh = ar + h * D_DIM + d0;
  float4 a0 = *(const float4*)alh, a1 = *(const float4*)(alh + 4);
  float4 r0 = *(const float4*)arh, r1 = *(const float4*)(arh + 4);
  float av[8] = {a0.x, a0.y, a0.z, a0.w, a1.x, a1.y, a1.z, a1.w};
  float rv[8] = {r0.x, r0.y, r0.z, r0.w, r1.x, r1.y, r1.z, r1.w};
  float sl = 0.f, sr = 0.f;
#pragma unroll
  for (int i = 0; i < 8; ++i) {
    sl = fmaf(fv[i], av[i], sl);
    sr = fmaf(fv[i], rv[i], sr);
  }
#pragma unroll
  for (int o = 1; o < 16; o <<= 1) {
    sl += __shfl_xor(sl, o);
    sr += __shfl_xor(sr, o);
  }
  if ((t & 15) == 0) {
    el[n * 4 + h] = sl;
    er[n * 4 + h] = sr;
  }
  // fp8 pack (HW converter; encode/decode use same format so roundtrip is consistent)
  int q0 = __builtin_amdgcn_cvt_pk_fp8_f32(fv[0], fv[1], 0, false);
  q0 = __builtin_amdgcn_cvt_pk_fp8_f32(fv[2], fv[3], q0, true);
  int q1 = __builtin_amdgcn_cvt_pk_fp8_f32(fv[4], fv[5], 0, false);
  q1 = __builtin_amdgcn_cvt_pk_fp8_f32(fv[6], fv[7], q1, true);
  uint2 qq;
  qq.x = (unsigned)q0;
  qq.y = (unsigned)q1;
  *(uint2*)(featq + (size_t)n * HD + t * 8) = qq;
}

// ---------------- CSR build ----------------
__global__ void histo_kernel(const int* __restrict__ dst, unsigned* __restrict__ deg) {
  int e = blockIdx.x * blockDim.x + threadIdx.x;
  if (e >= E_EDGES) return;
  atomicAdd(&deg[dst[e]], 1u);
}

// single-workgroup exclusive scan, 4 elems/thread (deg zero-padded to N_PAD)
__global__ void scan_kernel(const unsigned* __restrict__ deg, unsigned* __restrict__ off,
                            unsigned* __restrict__ cursor) {
  __shared__ unsigned warp_sums[16];
  __shared__ unsigned carry_s;
  const int tid = threadIdx.x;  // 1024
  const int wid = tid >> 6;
  if (tid == 0) carry_s = 0;
  __syncthreads();
  for (int base = 0; base < N_PAD; base += 4096) {
    int i = base + tid * 4;
    uint4 v = *(const uint4*)(deg + i);
    unsigned sm = v.x + v.y + v.z + v.w;
    unsigned x = sm;
#pragma unroll
    for (int o = 1; o < 64; o <<= 1) {
      unsigned y = __shfl_up(x, o);
      if ((tid & 63) >= o) x += y;
    }
    if ((tid & 63) == 63) warp_sums[wid] = x;
    __syncthreads();
    if (tid < 16) {
      unsigned s = warp_sums[tid];
#pragma unroll
      for (int o = 1; o < 16; o <<= 1) {
        unsigned y = __shfl_up(s, o);
        if (tid >= o) s += y;
      }
      warp_sums[tid] = s;
    }
    __syncthreads();
    unsigned carry = carry_s;
    unsigned wprev = (wid > 0) ? warp_sums[wid - 1] : 0u;
    unsigned ex = carry + wprev + (x - sm);
    uint4 o4;
    o4.x = ex;
    o4.y = ex + v.x;
    o4.z = o4.y + v.y;
    o4.w = o4.z + v.z;
    *(uint4*)(off + i) = o4;
    *(uint4*)(cursor + i) = o4;
    __syncthreads();
    if (tid == 0) carry_s = carry + warp_sums[15];
    __syncthreads();
  }
}

__global__ void scatter_kernel(const int* __restrict__ src, const int* __restrict__ dst,
                               unsigned* __restrict__ cursor, int* __restrict__ csr_src) {
  int e = blockIdx.x * blockDim.x + threadIdx.x;
  if (e >= E_EDGES) return;
  int d = dst[e];
  unsigned pos = atomicAdd(&cursor[d], 1u);
  csr_src[pos] = src[e];
}

// ---------------- fused edge-softmax + aggregate + bias/relu/head-mean ----------------
// 1 wave per node. thread t: head h=t>>4, dims d0=(t&15)*8 .. +7 (fp8 gather, 8B/thread)
__global__ __launch_bounds__(64) void agg_fused(const unsigned* __restrict__ off,
                                                const int* __restrict__ csr_src,
                                                const float* __restrict__ el,
                                                const float* __restrict__ er,
                                                const unsigned char* __restrict__ featq,
                                                const float* __restrict__ bias,
                                                unsigned short* __restrict__ hbuf) {
  __shared__ float4 ws4[64];
  const int n = blockIdx.x, t = threadIdx.x;
  const int h = t >> 4, d0 = (t & 15) * 8;
  const unsigned beg = off[n];
  const int deg = (int)(off[n + 1] - beg);
  const float NEG = -3.0e38f;
  float4 rr = *(const float4*)(er + (size_t)n * 4);
  float acc[8] = {};

  if (deg <= 64) {
    float4 v = {NEG, NEG, NEG, NEG};
    if (t < deg) {
      int s = csr_src[beg + t];
      float4 ll = *(const float4*)(el + (size_t)s * 4);
      v.x = lrelu(ll.x + rr.x);
      v.y = lrelu(ll.y + rr.y);
      v.z = lrelu(ll.z + rr.z);
      v.w = lrelu(ll.w + rr.w);
    }
    float m0 = v.x, m1 = v.y, m2 = v.z, m3 = v.w;
#pragma unroll
    for (int o = 32; o >= 1; o >>= 1) {
      m0 = fmaxf(m0, __shfl_xor(m0, o));
      m1 = fmaxf(m1, __shfl_xor(m1, o));
      m2 = fmaxf(m2, __shfl_xor(m2, o));
      m3 = fmaxf(m3, __shfl_xor(m3, o));
    }
    float4 ev = {0.f, 0.f, 0.f, 0.f};
    if (t < deg) {
      ev.x = __expf(v.x - m0);
      ev.y = __expf(v.y - m1);
      ev.z = __expf(v.z - m2);
      ev.w = __expf(v.w - m3);
    }
    float s0 = ev.x, s1 = ev.y, s2 = ev.z, s3 = ev.w;
#pragma unroll
    for (int o = 32; o >= 1; o >>= 1) {
      s0 += __shfl_xor(s0, o);
      s1 += __shfl_xor(s1, o);
      s2 += __shfl_xor(s2, o);
      s3 += __shfl_xor(s3, o);
    }
    if (t < deg) ws4[t] = ev;
    float invh = 1.0f / sel4(s0, s1, s2, s3, h);
    __syncthreads();
    int sj = (deg > 0) ? csr_src[beg] : 0;
    for (int j = 0; j < deg; ++j) {
      int sn = csr_src[beg + ((j + 1 < deg) ? j + 1 : j)];
      float4 wv = ws4[j];
      float w = sel4(wv.x, wv.y, wv.z, wv.w, h) * invh;
      uint2 q = *(const uint2*)(featq + (size_t)sj * HD + t * 8);
      f32x2 p0 = __builtin_amdgcn_cvt_pk_f32_fp8((int)q.x, false);
      f32x2 p1 = __builtin_amdgcn_cvt_pk_f32_fp8((int)q.x, true);
      f32x2 p2 = __builtin_amdgcn_cvt_pk_f32_fp8((int)q.y, false);
      f32x2 p3 = __builtin_amdgcn_cvt_pk_f32_fp8((int)q.y, true);
      acc[0] = fmaf(p0[0], w, acc[0]);
      acc[1] = fmaf(p0[1], w, acc[1]);
      acc[2] = fmaf(p1[0], w, acc[2]);
      acc[3] = fmaf(p1[1], w, acc[3]);
      acc[4] = fmaf(p2[0], w, acc[4]);
      acc[5] = fmaf(p2[1], w, acc[5]);
      acc[6] = fmaf(p3[0], w, acc[6]);
      acc[7] = fmaf(p3[1], w, acc[7]);
      sj = sn;
    }
  } else {
    // rare: 3-pass recompute path, correct for any degree
    float m[4] = {NEG, NEG, NEG, NEG};
    for (int j = t; j < deg; j += 64) {
      int s = csr_src[beg + j];
      float4 ll = *(const float4*)(el + (size_t)s * 4);
      m[0] = fmaxf(m[0], lrelu(ll.x + rr.x));
      m[1] = fmaxf(m[1], lrelu(ll.y + rr.y));
      m[2] = fmaxf(m[2], lrelu(ll.z + rr.z));
      m[3] = fmaxf(m[3], lrelu(ll.w + rr.w));
    }
#pragma unroll
    for (int o = 32; o >= 1; o >>= 1) {
      m[0] = fmaxf(m[0], __shfl_xor(m[0], o));
      m[1] = fmaxf(m[1], __shfl_xor(m[1], o));
      m[2] = fmaxf(m[2], __shfl_xor(m[2], o));
      m[3] = fmaxf(m[3], __shfl_xor(m[3], o));
    }
    float sm[4] = {0.f, 0.f, 0.f, 0.f};
    for (int j = t; j < deg; j += 64) {
      int s = csr_src[beg + j];
      float4 ll = *(const float4*)(el + (size_t)s * 4);
      sm[0] += __expf(lrelu(ll.x + rr.x) - m[0]);
      sm[1] += __expf(lrelu(ll.y + rr.y) - m[1]);
      sm[2] += __expf(lrelu(ll.z + rr.z) - m[2]);
      sm[3] += __expf(lrelu(ll.w + rr.w) - m[3]);
    }
#pragma unroll
    for (int o = 32; o >= 1; o >>= 1) {
      sm[0] += __shfl_xor(sm[0], o);
      sm[1] += __shfl_xor(sm[1], o);
      sm[2] += __shfl_xor(sm[2], o);
      sm[3] += __shfl_xor(sm[3], o);
    }
    float mh = sel4(m[0], m[1], m[2], m[3], h);
    float ih = 1.0f / sel4(sm[0], sm[1], sm[2], sm[3], h);
    float rrh = sel4(rr.x, rr.y, rr.z, rr.w, h);
    for (int j = 0; j < deg; ++j) {
      int sj = csr_src[beg + j];
      float llh = el[(size_t)sj * 4 + h];
      float w = __expf(lrelu(llh + rrh) - mh) * ih;
      uint2 q = *(const uint2*)(featq + (size_t)sj * HD + t * 8);
      f32x2 p0 = __builtin_amdgcn_cvt_pk_f32_fp8((int)q.x, false);
      f32x2 p1 = __builtin_amdgcn_cvt_pk_f32_fp8((int)q.x, true);
      f32x2 p2 = __builtin_amdgcn_cvt_pk_f32_fp8((int)q.y, false);
      f32x2 p3 = __builtin_amdgcn_cvt_pk_f32_fp8((int)q.y, true);
      acc[0] = fmaf(p0[0], w, acc[0]);
      acc[1] = fmaf(p0[1], w, acc[1]);
      acc[2] = fmaf(p1[0], w, acc[2]);
      acc[3] = fmaf(p1[1], w, acc[3]);
      acc[4] = fmaf(p2[0], w, acc[4]);
      acc[5] = fmaf(p2[1], w, acc[5]);
      acc[6] = fmaf(p3[0], w, acc[6]);
      acc[7] = fmaf(p3[1], w, acc[7]);
    }
  }

  // epilogue: +bias, relu, mean over heads (lanes t, t^16, t^32, t^48 share d-range)
  const float* bp = bias + h * D_DIM + d0;
  float4 b0 = *(const float4*)bp, b1 = *(const float4*)(bp + 4);
  float bv[8] = {b0.x, b0.y, b0.z, b0.w, b1.x, b1.y, b1.z, b1.w};
  float r[8];
#pragma unroll
  for (int i = 0; i < 8; ++i) r[i] = fmaxf(acc[i] + bv[i], 0.f);
#pragma unroll
  for (int i = 0; i < 8; ++i) {
    r[i] += __shfl_xor(r[i], 16);
    r[i] += __shfl_xor(r[i], 32);
  }
  if (h == 0) {
    uint4 o;
    o.x = (unsigned)f2b(r[0] * 0.25f) | ((unsigned)f2b(r[1] * 0.25f) << 16);
    o.y = (unsigned)f2b(r[2] * 0.25f) | ((unsigned)f2b(r[3] * 0.25f) << 16);
    o.z = (unsigned)f2b(r[4] * 0.25f) | ((unsigned)f2b(r[5] * 0.25f) << 16);
    o.w = (unsigned)f2b(r[6] * 0.25f) | ((unsigned)f2b(r[7] * 0.25f) << 16);
    *(uint4*)(hbuf + (size_t)n * D_DIM + d0) = o;
  }
}

// ---------------- readout ----------------
__global__ void colsum(const unsigned short* __restrict__ hbuf, float* __restrict__ hg) {
  int d = threadIdx.x;  // 128
  float s = 0.0f;
  for (int n = blockIdx.x; n < N_NODES; n += gridDim.x)
    s += b2f(hbuf[(size_t)n * D_DIM + d]);
  atomicAdd(&hg[d], s);
}

__global__ void final_k(const float* __restrict__ hg, const float* __restrict__ Wc,
                        const float* __restrict__ bc, float* __restrict__ out) {
  int l = threadIdx.x;  // 64
  float v = hg[l] * Wc[l] + hg[l + 64] * Wc[l + 64];
#pragma unroll
  for (int off = 32; off >= 1; off >>= 1) v += __shfl_xor(v, off);
  if (l == 0) {
    float x = v * (1.0f / N_NODES) + bc[0];
    out[0] = 1.0f / (1.0f + expf(-x));
  }
}

extern "C" void kernel_launch(void* const* d_in, const int* in_sizes, int n_in,
                              void* d_out, int out_size, void* d_ws, size_t ws_size,
                              hipStream_t stream) {
  const float* nfeats = (const float*)d_in[0];
  const float* W1 = (const float*)d_in[1];
  const float* al1 = (const float*)d_in[2];
  const float* ar1 = (const float*)d_in[3];
  const float* b1 = (const float*)d_in[4];
  const float* W2 = (const float*)d_in[5];
  const float* al2 = (const float*)d_in[6];
  const float* ar2 = (const float*)d_in[7];
  const float* b2 = (const float*)d_in[8];
  const float* W3 = (const float*)d_in[9];
  const float* al3 = (const float*)d_in[10];
  const float* ar3 = (const float*)d_in[11];
  const float* b3 = (const float*)d_in[12];
  const float* Wc = (const float*)d_in[13];
  const float* bc = (const float*)d_in[14];
  const int* src = (const int*)d_in[15];
  const int* dst = (const int*)d_in[16];
  float* out = (float*)d_out;

  // ---- workspace carve (256B aligned regions) ----
  char* p = (char*)d_ws;
  auto carve = [&](size_t bytes) {
    char* r = p;
    p += (bytes + 255) & ~(size_t)255;
    return r;
  };
  float* el = (float*)carve((size_t)N_NODES * 4 * 4);
  float* er = (float*)carve((size_t)N_NODES * 4 * 4);
  float* hg = (float*)carve(512);
  unsigned* deg = (unsigned*)carve((size_t)N_PAD * 4);
  unsigned* offv = (unsigned*)carve((size_t)(N_PAD + 4) * 4);
  unsigned* cursor = (unsigned*)carve((size_t)N_PAD * 4);
  int* csr_src = (int*)carve((size_t)E_EDGES * 4);
  unsigned short* featb = (unsigned short*)carve((size_t)N_NODES * HD * 2);
  unsigned char* featq = (unsigned char*)carve((size_t)N_NODES * HD);
  unsigned short* hbufb = (unsigned short*)carve((size_t)N_NODES * D_DIM * 2);
  unsigned short* xb = (unsigned short*)carve((size_t)(N_NODES + 128) * 256 * 2);
  unsigned short* WT1 = (unsigned short*)carve((size_t)HD * 256 * 2);
  unsigned short* WT2 = (unsigned short*)carve((size_t)HD * 128 * 2);
  unsigned short* WT3 = (unsigned short*)carve((size_t)HD * 128 * 2);

  // ---- build CSR once (dst constant across layers) ----
  hipMemsetAsync(deg, 0, (size_t)N_PAD * sizeof(unsigned), stream);
  histo_kernel<<<(E_EDGES + 255) / 256, 256, 0, stream>>>(dst, deg);
  scan_kernel<<<1, 1024, 0, stream>>>(deg, offv, cursor);
  scatter_kernel<<<(E_EDGES + 255) / 256, 256, 0, stream>>>(src, dst, cursor, csr_src);

  // input cast + all weight transposes up front
  cast_f2b<<<(N_NODES * 256 / 4 + 255) / 256, 256, 0, stream>>>(nfeats, xb, N_NODES * 256 / 4);
  transpose_cast<<<(256 * HD + 255) / 256, 256, 0, stream>>>(W1, WT1, 256);
  transpose_cast<<<(128 * HD + 255) / 256, 256, 0, stream>>>(W2, WT2, 128);
  transpose_cast<<<(128 * HD + 255) / 256, 256, 0, stream>>>(W3, WT3, 128);

  auto run_layer = [&](const unsigned short* X, int K, const unsigned short* WT,
                       const float* alv, const float* arv, const float* bv) {
    dim3 g((N_NODES + 127) / 128, HD / 128);
    gemm_mfma<<<g, 256, 0, stream>>>(X, WT, featb, K);
    eler_cast<<<N_NODES, 64, 0, stream>>>(featb, alv, arv, el, er, featq);
    agg_fused<<<N_NODES, 64, 0, stream>>>(offv, csr_src, el, er, featq, bv, hbufb);
  };

  run_layer(xb, 256, WT1, al1, ar1, b1);
  run_layer(hbufb, 128, WT2, al2, ar2, b2);
  run_layer(hbufb, 128, WT3, al3, ar3, b3);

  hipMemsetAsync(hg, 0, 512, stream);
  colsum<<<1024, 128, 0, stream>>>(hbufb, hg);
  final_k<<<1, 64, 0, stream>>>(hg, Wc, bc, out);
}